// Round 6
// baseline (482.110 us; speedup 1.0000x reference)
//
#include <hip/hip_runtime.h>
#include <hip/hip_bf16.h>
#include <math.h>

typedef __hip_bfloat16 bf16;
typedef short s16x8 __attribute__((ext_vector_type(8)));
typedef float f32x4 __attribute__((ext_vector_type(4)));

#define NQ 200
#define SEQ 8
#define DM 2048
#define OUTD 1152
#define LT 28
#define M_ALL 6300
#define SM 5600
#define SN_PAD 768
#define ATT_STRIDE 720
#define N2 2304          // W viewed as [2304, 2048]
#define KP 160
#define CH_Q 50
#define CH_ROWS 1400
#define CH_MPAD 1408
#define ABLK 144         // attn per-class column block (16B-aligned)

__device__ __forceinline__ float bf2f(bf16 v) { return __bfloat162float(v); }
__device__ __forceinline__ bf16 f2bf(float v) { return __float2bfloat16(v); }
__device__ __forceinline__ float ubits2f(unsigned int u16) {
    unsigned int i = u16 << 16;
    float f; __builtin_memcpy(&f, &i, 4); return f;
}
__device__ __forceinline__ unsigned short f2bits(float f) {
    bf16 b = __float2bfloat16(f);
    unsigned short u; __builtin_memcpy(&u, &b, 2); return u;
}

__device__ const int TUP_A[LT] = {0,0,0,0,0,0,0,1,1,1,1,1,1,2,2,2,2,2,3,3,3,3,4,4,4,5,5,6};
__device__ const int TUP_B[LT] = {1,2,3,4,5,6,7,2,3,4,5,6,7,3,4,5,6,7,4,5,6,7,5,6,7,6,7,7};

// ---------------------------------------------------------------------------
// fused weight convert: [k_w | v_w] fp32 -> bf16 (2 x 1,179,648 float4)
// ---------------------------------------------------------------------------
__global__ __launch_bounds__(256) void wconv2_k(const float4* __restrict__ kw,
                                                const float4* __restrict__ vw,
                                                ushort4* __restrict__ o) {
    int i = blockIdx.x * 256 + threadIdx.x;     // 0 .. 2,359,295
    float4 v = (i < 1179648) ? kw[i] : vw[i - 1179648];
    ushort4 r;
    r.x = f2bits(v.x); r.y = f2bits(v.y); r.z = f2bits(v.z); r.w = f2bits(v.w);
    o[i] = r;
}

// ---------------------------------------------------------------------------
// pe table: pe[s][d], 8 x 2048 fp32 (trig computed once, not 1800x).
// Also zeroes attn tail rows 5600..5631 (never written by softmax; the proto
// GEMM's K-spill reads next-row cols 0..15, so uninit bf16 there could be
// NaN and NaN*0 would poison protoc row 1399).
// ---------------------------------------------------------------------------
__global__ __launch_bounds__(256) void pe_k(float* __restrict__ pe,
                                            bf16* __restrict__ attn_tail) {
    int i = blockIdx.x * 256 + threadIdx.x;     // 0 .. 16383
    int s = i >> 11, d = i & 2047;
    float dv = expf((float)(d & ~1) * (-9.210340371976184f / 2048.0f));
    float ang = (float)s * dv;
    pe[i] = (d & 1) ? cosf(ang) * 0.1f : sinf(ang) * 0.1f;
    for (int j = i; j < 32 * ATT_STRIDE; j += 64 * 256) attn_tail[j] = f2bf(0.f);
}

// ---------------------------------------------------------------------------
// pexb[r][d] = fp32 src[n][s][d] + pe[s][d] -> bf16 (1800 rows, vectorized)
// ---------------------------------------------------------------------------
__global__ __launch_bounds__(256) void pex_k(const float* __restrict__ sup,
                                             const float* __restrict__ qry,
                                             const float* __restrict__ pe,
                                             bf16* __restrict__ pexb) {
    int r = blockIdx.x, t = threadIdx.x;
    int n, s;
    const float* src;
    if (r < 200) { n = r >> 3; s = r & 7; src = sup; }
    else { int rr = r - 200; n = rr >> 3; s = rr & 7; src = qry; }
    const float4* row = (const float4*)(src + ((size_t)n * SEQ + s) * DM);
    const float4* per = (const float4*)(pe + (size_t)s * DM);
    ushort4* orow = (ushort4*)(pexb + (size_t)r * DM);
    for (int d = t; d < DM / 4; d += 256) {
        float4 a = row[d], p = per[d];
        ushort4 o;
        o.x = f2bits(a.x + p.x); o.y = f2bits(a.y + p.y);
        o.z = f2bits(a.z + p.z); o.w = f2bits(a.w + p.w);
        orow[d] = o;
    }
}

// ---------------------------------------------------------------------------
// Generic MFMA bf16 GEMM: C = scale*A*B^T; z shifts A/B/C by aZ/bZ/cZ elems.
// LDS-FREE: MFMA fragments are loaded DIRECTLY global->VGPR.  Rationale
// (round-5 post-mortem): the staged kernel issues 12 wave LDS b128 ops per
// 16 MFMAs -> ~384 shared-LDS-pipe cycles per block K-step vs 78 cy of MFMA
// wall time; every staging schedule (2-barrier 74.8us, gload_lds 116/128us,
// 2-deep 86.5us, 1-barrier dbuf 85.2us) hit the same LDS/barrier wall.
// LDS only provided 2x cross-wave reuse; L1/L2 (XCD-swizzled, panels are
// L2-resident) now provide it instead.  Fragment read pattern per load:
// 64 lanes = 16 rows x 64 contiguous B -> same coalescing class as staging.
// Depth-2 software pipeline: 3 named frag sets (p/q/r), all indices static,
// zero barriers, compiler schedules vmcnt freely.
// Requires K >= 32, K % 32 == 0, all bases/ld/z 16B-aligned.
// Prefetch never reads past the allocated workspace at any call site
// (verified: spill lands in adjacent live regions; values never enter MFMA).
// C rows >= mlim are not stored (M-pad garbage containment).
// ---------------------------------------------------------------------------
__global__ __launch_bounds__(256) void gemm_bt(
    const bf16* __restrict__ A, int lda, size_t aZ,
    const bf16* __restrict__ B, int ldb, size_t bZ,
    float scale, bf16* __restrict__ C, int ldc, size_t cZ, int K, int mlim) {
    // ---- XCD swizzle: logical tile id lg from hw block id (bijective) ----
    const int gx = gridDim.x, gy = gridDim.y;
    const int nwg = gx * gy * (int)gridDim.z;
    const int orig = ((int)blockIdx.z * gy + blockIdx.y) * gx + blockIdx.x;
    const int qc = nwg >> 3, rc = nwg & 7;
    const int xcd = orig & 7, sub = orig >> 3;
    const int lg = (xcd < rc ? xcd * (qc + 1) : rc * (qc + 1) + (xcd - rc) * qc) + sub;
    const int bx = lg % gx;
    const int rest = lg / gx;
    const int by = rest % gy, bz = rest / gy;

    const int tile_m = bx * 128, tile_n = by * 128;
    const int t = threadIdx.x, lane = t & 63, wave = t >> 6;
    const int wm = (wave & 1) * 64, wn = (wave >> 1) * 64;
    const int fr = lane & 15, quad = lane >> 4;

    // per-lane fragment bases: row (tile+w*+fr), col-segment quad*8
    const unsigned short* Ab = (const unsigned short*)A + aZ * bz
                               + (size_t)(tile_m + wm + fr) * lda + quad * 8;
    const unsigned short* Bb = (const unsigned short*)B + bZ * bz
                               + (size_t)(tile_n + wn + fr) * ldb + quad * 8;
    const size_t a16 = (size_t)16 * lda, b16 = (size_t)16 * ldb;
    const size_t cbase = cZ * bz;

    f32x4 acc[4][4];
#pragma unroll
    for (int i = 0; i < 4; i++)
#pragma unroll
        for (int j = 0; j < 4; j++) acc[i][j] = {0.f, 0.f, 0.f, 0.f};

    s16x8 pa[4], pb[4], qa[4], qb[4], ra_[4], rb_[4];

#define LOADF(sa, sb, k0) do {                                                  \
    _Pragma("unroll")                                                           \
    for (int i = 0; i < 4; i++) {                                               \
        sa[i] = *(const s16x8*)(Ab + (size_t)i * a16 + (size_t)(k0));           \
        sb[i] = *(const s16x8*)(Bb + (size_t)i * b16 + (size_t)(k0));           \
    }                                                                           \
  } while (0)

#define MM(sa, sb) do {                                                         \
    _Pragma("unroll")                                                           \
    for (int i = 0; i < 4; i++)                                                 \
    _Pragma("unroll")                                                           \
        for (int j = 0; j < 4; j++)                                             \
            acc[i][j] = __builtin_amdgcn_mfma_f32_16x16x32_bf16(sa[i], sb[j], acc[i][j], 0, 0, 0); \
  } while (0)

    const int nIter = K >> 5;              // 32-K steps; tile s -> set (s%3)
    LOADF(pa, pb, 0);
    if (nIter > 1) LOADF(qa, qb, 32);
    if (nIter > 2) LOADF(ra_, rb_, 64);
    for (int s = 0; s < nIter; s += 3) {   // all guards wave-uniform
        MM(pa, pb);
        if (s + 3 < nIter) LOADF(pa, pb, (s + 3) * 32);
        if (s + 1 < nIter) {
            MM(qa, qb);
            if (s + 4 < nIter) LOADF(qa, qb, (s + 4) * 32);
        }
        if (s + 2 < nIter) {
            MM(ra_, rb_);
            if (s + 5 < nIter) LOADF(ra_, rb_, (s + 5) * 32);
        }
    }
#undef LOADF
#undef MM

    const int rb = quad * 4;
#pragma unroll
    for (int i = 0; i < 4; i++)
#pragma unroll
        for (int j = 0; j < 4; j++) {
            const int col = tile_n + wn + j * 16 + fr;
#pragma unroll
            for (int r = 0; r < 4; r++) {
                const int row = tile_m + wm + i * 16 + rb + r;
                if (row < mlim)
                    C[cbase + (size_t)row * ldc + col] = f2bf(acc[i][j][r] * scale);
            }
        }
}

// ---------------------------------------------------------------------------
// combine_k: ks[m][n] = LN(Yk[ra][2n] + Yk[rb][2n+1] + kb[n])
// ---------------------------------------------------------------------------
__global__ __launch_bounds__(256) void combine_k(
    const unsigned int* __restrict__ Yk, const float* __restrict__ kb,
    const float* __restrict__ lng, const float* __restrict__ lnb,
    bf16* __restrict__ ks) {
    const int m = blockIdx.x, t = threadIdx.x, lane = t & 63, wave = t >> 6;
    int mm = m < 700 ? m : m - 700;
    int base = m < 700 ? 0 : 200;
    int nsamp = mm / LT, l = mm - nsamp * LT;
    const unsigned int* ya = Yk + (size_t)(base + nsamp * 8 + TUP_A[l]) * (N2 / 2);
    const unsigned int* yb = Yk + (size_t)(base + nsamp * 8 + TUP_B[l]) * (N2 / 2);
    float vals[5];
    int cnt = 0;
    float s = 0.f, s2 = 0.f;
    for (int n = t; n < OUTD; n += 256) {
        unsigned int ua = ya[n], ub = yb[n];
        float vk = ubits2f(ua & 0xFFFFu) + ubits2f(ub >> 16) + kb[n];
        vals[cnt++] = vk;
        s += vk; s2 += vk * vk;
    }
    for (int o = 32; o > 0; o >>= 1) { s += __shfl_xor(s, o); s2 += __shfl_xor(s2, o); }
    __shared__ float r1[4], r2[4];
    if (lane == 0) { r1[wave] = s; r2[wave] = s2; }
    __syncthreads();
    s = r1[0] + r1[1] + r1[2] + r1[3];
    s2 = r2[0] + r2[1] + r2[2] + r2[3];
    float mu = s * (1.f / OUTD);
    float var = s2 * (1.f / OUTD) - mu * mu;
    float inv = rsqrtf(fmaxf(var, 0.f) + 1e-5f);
    cnt = 0;
    for (int n = t; n < OUTD; n += 256)
        ks[(size_t)m * OUTD + n] = f2bf((vals[cnt++] - mu) * inv * lng[n] + lnb[n]);
}

// ---------------------------------------------------------------------------
// combine_v: vs[m][n] = Yv[ra][2n] + Yv[rb][2n+1] + vb[n]
// ---------------------------------------------------------------------------
__global__ __launch_bounds__(256) void combine_v(
    const unsigned int* __restrict__ Yv, const float* __restrict__ vb,
    bf16* __restrict__ vs) {
    const int m = blockIdx.x, t = threadIdx.x;
    int mm = m < 700 ? m : m - 700;
    int base = m < 700 ? 0 : 200;
    int nsamp = mm / LT, l = mm - nsamp * LT;
    const unsigned int* ya = Yv + (size_t)(base + nsamp * 8 + TUP_A[l]) * (N2 / 2);
    const unsigned int* yb = Yv + (size_t)(base + nsamp * 8 + TUP_B[l]) * (N2 / 2);
    for (int n = t; n < OUTD; n += 256) {
        unsigned int ua = ya[n], ub = yb[n];
        vs[(size_t)m * OUTD + n] =
            f2bf(ubits2f(ua & 0xFFFFu) + ubits2f(ub >> 16) + vb[n]);
    }
}

// ---------------------------------------------------------------------------
// softmax: one WAVE per (row, class): 140 = 64+64+12 elems/lane-slot; pure
// 64-lane shuffle reductions, ZERO barriers (was ~15 __syncthreads/block).
// attn laid out as 5 x 144-col blocks; cols 140..143 of each block zeroed.
// ---------------------------------------------------------------------------
__global__ __launch_bounds__(320) void softmax_k(const bf16* __restrict__ sc,
                                                 bf16* __restrict__ attn) {
    const int row = blockIdx.x, w = threadIdx.x >> 6, lane = threadIdx.x & 63;
    const bf16* src = sc + (size_t)row * SN_PAD + w * 140;
    bf16* dst = attn + (size_t)row * ATT_STRIDE + w * ABLK;
    float a = bf2f(src[lane]);
    float b = bf2f(src[lane + 64]);            // lane+64 <= 127 < 140: valid
    float c = (lane < 12) ? bf2f(src[lane + 128]) : -3.0e38f;
    float m = fmaxf(fmaxf(a, b), c);
    for (int o = 32; o > 0; o >>= 1) m = fmaxf(m, __shfl_xor(m, o));
    float ea = __expf(a - m), eb = __expf(b - m);
    float ec = (lane < 12) ? __expf(c - m) : 0.f;
    float s = ea + eb + ec;
    for (int o = 32; o > 0; o >>= 1) s += __shfl_xor(s, o);
    float inv = 1.f / s;
    dst[lane] = f2bf(ea * inv);
    dst[lane + 64] = f2bf(eb * inv);
    if (lane < 16) dst[lane + 128] = f2bf(lane < 12 ? ec * inv : 0.f);
}

// ---------------------------------------------------------------------------
// vsp[w][d][j] = vs[w*140+j][d] (j>=140 -> 0); block 0 also zeroes gbuf
// ---------------------------------------------------------------------------
__global__ __launch_bounds__(256) void vspad_k(const bf16* __restrict__ vs,
                                               bf16* __restrict__ vp,
                                               float* __restrict__ gbuf) {
    int idx = blockIdx.x * 256 + threadIdx.x;
    if (blockIdx.x == 0)
        for (int i = threadIdx.x; i < NQ * 21; i += 256) gbuf[i] = 0.f;
    if (idx >= 5 * OUTD * KP) return;
    int j = idx % KP;
    int rest = idx / KP;
    int dcol = rest % OUTD;
    int w = rest / OUTD;
    vp[idx] = (j < 140) ? vs[(size_t)(w * 140 + j) * OUTD + dcol] : f2bf(0.f);
}

// ---------------------------------------------------------------------------
// Gram reduce over a proto chunk -> 21 sufficient stats per query.
// Vectorized: s16x8 (16B) loads, 2 tuple-rows per block, grid (50,14).
// Rows are 1152 bf16 = 2304 B (16B-aligned), so 16B loads are safe.
// ---------------------------------------------------------------------------
__global__ __launch_bounds__(256) void gramred_k(const bf16* __restrict__ protoc,
                                                 const bf16* __restrict__ vs,
                                                 float* __restrict__ gbuf,
                                                 int row0, int q0) {
    const int ql = blockIdx.x;          // 0..49
    const int lgb = blockIdx.y;         // 0..13 (2 tuple-rows each)
    const int t = threadIdx.x, lane = t & 63, wave = t >> 6;
    const size_t PZ = (size_t)CH_MPAD * OUTD;
    float g[15] = {0.f};
    float h[5] = {0.f, 0.f, 0.f, 0.f, 0.f};
    float e = 0.f;
    for (int idx = t; idx < 2 * OUTD / 8; idx += 256) {   // 288 16B-slots
        int li = idx / 144;
        int dv = idx - li * 144;
        int l = lgb * 2 + li;
        size_t ml = (size_t)(ql * LT + l) * OUTD + dv * 8;
        s16x8 pw0 = *(const s16x8*)&protoc[0 * PZ + ml];
        s16x8 pw1 = *(const s16x8*)&protoc[1 * PZ + ml];
        s16x8 pw2 = *(const s16x8*)&protoc[2 * PZ + ml];
        s16x8 pw3 = *(const s16x8*)&protoc[3 * PZ + ml];
        s16x8 pw4 = *(const s16x8*)&protoc[4 * PZ + ml];
        s16x8 vv = *(const s16x8*)&vs[(size_t)(700 + row0 + ql * LT + l) * OUTD + dv * 8];
#pragma unroll
        for (int ee = 0; ee < 8; ee++) {
            float pv[5];
            pv[0] = ubits2f((unsigned short)pw0[ee]);
            pv[1] = ubits2f((unsigned short)pw1[ee]);
            pv[2] = ubits2f((unsigned short)pw2[ee]);
            pv[3] = ubits2f((unsigned short)pw3[ee]);
            pv[4] = ubits2f((unsigned short)pw4[ee]);
            float v = ubits2f((unsigned short)vv[ee]);
            e += v * v;
            int c = 0;
#pragma unroll
            for (int a = 0; a < 5; a++) {
                h[a] += v * pv[a];
#pragma unroll
                for (int b = a; b < 5; b++) g[c++] += pv[a] * pv[b];
            }
        }
    }
    float vals[21];
#pragma unroll
    for (int k = 0; k < 15; k++) vals[k] = g[k];
#pragma unroll
    for (int k = 0; k < 5; k++) vals[15 + k] = h[k];
    vals[20] = e;
#pragma unroll
    for (int k = 0; k < 21; k++)
        for (int o = 32; o > 0; o >>= 1) vals[k] += __shfl_xor(vals[k], o);
    __shared__ float red[4][21];
    if (lane == 0)
#pragma unroll
        for (int k = 0; k < 21; k++) red[wave][k] = vals[k];
    __syncthreads();
    if (t < 21) {
        float s = red[0][t] + red[1][t] + red[2][t] + red[3][t];
        atomicAdd(&gbuf[(q0 + ql) * 21 + t], s);
    }
}

// ---------------------------------------------------------------------------
// out (fp32): per q -> 25 sim + 5 ori
// ---------------------------------------------------------------------------
__global__ __launch_bounds__(64) void out_k(const float* __restrict__ gbuf,
                                            float* __restrict__ out) {
    int q = blockIdx.x;
    if (threadIdx.x != 0) return;
    const float* r = gbuf + q * 21;
    float G[5][5];
    int c = 0;
    for (int a = 0; a < 5; a++)
        for (int b = a; b < 5; b++) { G[a][b] = r[c]; G[b][a] = r[c]; c++; }
    float e = r[20];
    float nrm[5];
    for (int a = 0; a < 5; a++) nrm[a] = sqrtf(fmaxf(G[a][a], 0.f));
    for (int a = 0; a < 5; a++)
        for (int b = 0; b < 5; b++)
            out[(size_t)q * 25 + a * 5 + b] = G[a][b] / fmaxf(nrm[a] * nrm[b], 1e-8f);
    for (int w = 0; w < 5; w++)
        out[5000 + (size_t)q * 5 + w] = -(e - 2.f * r[15 + w] + G[w][w]) * (1.f / 28.f);
}

// ---------------------------------------------------------------------------
extern "C" void kernel_launch(void* const* d_in, const int* in_sizes, int n_in,
                              void* d_out, int out_size, void* d_ws, size_t ws_size,
                              hipStream_t stream) {
    const float* sup = (const float*)d_in[0];
    // d_in[1] = support_labels int32 — unused (sorted equal-shot)
    const float* qry = (const float*)d_in[2];
    const float* k_w = (const float*)d_in[3];
    const float* k_b = (const float*)d_in[4];
    const float* v_w = (const float*)d_in[5];
    const float* v_b = (const float*)d_in[6];
    const float* lng = (const float*)d_in[7];
    const float* lnb = (const float*)d_in[8];
    (void)in_sizes; (void)n_in; (void)out_size; (void)ws_size;

    // layout (bytes), peak 49,421,728 (<= verified ws_size >= 54.5 MB):
    //   pexb   @0           7,864,320 (1920 rows; 1800 real)  dead after proj
    //   wbf    @7,864,320  18,874,368 (k|v bf16)              dead after proj
    //   Yk     @26,738,688  8,294,400 (1800x2304)             dead after comb_k
    //   Yv     @35,033,088  8,294,400                         dead after comb_v
    //   ks     @0          14,588,928 (6332 rows; 6300 real)  dead after scores
    //   vs     @16,220,160 14,515,200 (6300 rows)             live to end
    //   sc     @30,735,360  8,650,752 (over dead Yk/Yv head)  dead after softmax
    //   vsp    @39,386,112  1,843,200
    //   attn   @41,229,312  8,110,080 (5632 rows x 720; 5 x 144-col blocks)
    //   gbuf   @49,339,392     16,800
    //   pe     @49,356,192     65,536 (8x2048 fp32 table)
    //   protoc @0          16,220,160 (over dead ks, after scores)
    char* ws = (char*)d_ws;
    bf16* pexb   = (bf16*)(ws + 0);
    bf16* wbf    = (bf16*)(ws + 7864320);
    bf16* Yk     = (bf16*)(ws + 26738688);
    bf16* Yv     = (bf16*)(ws + 35033088);
    bf16* ks     = (bf16*)(ws + 0);
    bf16* vs     = (bf16*)(ws + 16220160);
    bf16* sc     = (bf16*)(ws + 30735360);
    bf16* vsp    = (bf16*)(ws + 39386112);
    bf16* attn   = (bf16*)(ws + 41229312);
    float* gbuf  = (float*)(ws + 49339392);
    float* pe    = (float*)(ws + 49356192);
    bf16* protoc = (bf16*)(ws + 0);

    pe_k<<<dim3(64), dim3(256), 0, stream>>>(pe, attn + (size_t)SM * ATT_STRIDE);
    pex_k<<<dim3(1800), dim3(256), 0, stream>>>(sup, qry, pe, pexb);
    wconv2_k<<<dim3(9216), dim3(256), 0, stream>>>(
        (const float4*)k_w, (const float4*)v_w, (ushort4*)wbf);

    // fused K+V projection: z in {k,v}; Y[1800,2304] = pexb @ W_view^T
    gemm_bt<<<dim3(15, 18, 2), dim3(256), 0, stream>>>(
        pexb, DM, 0, wbf, DM, (size_t)4718592,
        1.0f, Yk, N2, (size_t)4147200, DM, 1800);

    combine_k<<<dim3(M_ALL), dim3(256), 0, stream>>>(
        (const unsigned int*)Yk, k_b, lng, lnb, ks);
    combine_v<<<dim3(M_ALL), dim3(256), 0, stream>>>(
        (const unsigned int*)Yv, v_b, vs);

    // scores: ks_q[5632,1152] @ ks_s[768,1152]^T / sqrt(1152)
    gemm_bt<<<dim3(44, 6, 1), dim3(256), 0, stream>>>(
        ks + (size_t)700 * OUTD, OUTD, 0, ks, OUTD, 0,
        0.029462782549439484f, sc, SN_PAD, 0, OUTD, 5632);

    vspad_k<<<dim3((5 * OUTD * KP + 255) / 256), dim3(256), 0, stream>>>(
        vs, vsp, gbuf);
    softmax_k<<<dim3(SM), dim3(320), 0, stream>>>(sc, attn);

    // proto chunks: 4 x 50 queries; per-class GEMM then Gram reduce
    // A = attn with 144-col class blocks (aZ=144, 16B-aligned); K=160 reads
    // spill 16 cols into the next block where vsp's zero columns kill them.
    for (int c = 0; c < 4; c++) {
        gemm_bt<<<dim3(11, 9, 5), dim3(256), 0, stream>>>(
            attn + (size_t)c * CH_ROWS * ATT_STRIDE, ATT_STRIDE, (size_t)ABLK,
            vsp, KP, (size_t)OUTD * KP,
            1.0f, protoc, OUTD, (size_t)CH_MPAD * OUTD, KP, CH_MPAD);
        gramred_k<<<dim3(CH_Q, 14), dim3(256), 0, stream>>>(
            protoc, vs, gbuf, c * CH_ROWS, c * CH_Q);
    }

    out_k<<<dim3(NQ), dim3(64), 0, stream>>>(gbuf, (float*)d_out);
}

// Round 7
// 339.130 us; speedup vs baseline: 1.4216x; 1.4216x over previous
//
#include <hip/hip_runtime.h>
#include <hip/hip_bf16.h>
#include <math.h>

typedef __hip_bfloat16 bf16;
typedef short s16x8 __attribute__((ext_vector_type(8)));
typedef float f32x4 __attribute__((ext_vector_type(4)));

#define NQ 200
#define SEQ 8
#define DM 2048
#define OUTD 1152
#define LT 28
#define M_ALL 6300
#define SM 5600
#define SN_PAD 768
#define ATT_STRIDE 720
#define N2 2304          // W viewed as [2304, 2048]
#define KP 160
#define CH_Q 50
#define CH_ROWS 1400
#define CH_MPAD 1408
#define ABLK 144         // attn per-class column block (16B-aligned)

__device__ __forceinline__ float bf2f(bf16 v) { return __bfloat162float(v); }
__device__ __forceinline__ bf16 f2bf(float v) { return __float2bfloat16(v); }
__device__ __forceinline__ float ubits2f(unsigned int u16) {
    unsigned int i = u16 << 16;
    float f; __builtin_memcpy(&f, &i, 4); return f;
}
__device__ __forceinline__ unsigned short f2bits(float f) {
    bf16 b = __float2bfloat16(f);
    unsigned short u; __builtin_memcpy(&u, &b, 2); return u;
}

__device__ const int TUP_A[LT] = {0,0,0,0,0,0,0,1,1,1,1,1,1,2,2,2,2,2,3,3,3,3,4,4,4,5,5,6};
__device__ const int TUP_B[LT] = {1,2,3,4,5,6,7,2,3,4,5,6,7,3,4,5,6,7,4,5,6,7,5,6,7,6,7,7};

// ---------------------------------------------------------------------------
// fused weight convert: [k_w | v_w] fp32 -> bf16 (2 x 1,179,648 float4)
// ---------------------------------------------------------------------------
__global__ __launch_bounds__(256) void wconv2_k(const float4* __restrict__ kw,
                                                const float4* __restrict__ vw,
                                                ushort4* __restrict__ o) {
    int i = blockIdx.x * 256 + threadIdx.x;     // 0 .. 2,359,295
    float4 v = (i < 1179648) ? kw[i] : vw[i - 1179648];
    ushort4 r;
    r.x = f2bits(v.x); r.y = f2bits(v.y); r.z = f2bits(v.z); r.w = f2bits(v.w);
    o[i] = r;
}

// ---------------------------------------------------------------------------
// pe table: pe[s][d], 8 x 2048 fp32 (trig computed once, not 1800x).
// Also zeroes attn tail rows 5600..5631 (never written by softmax; the proto
// GEMM's K-spill reads next-row cols 0..15, so uninit bf16 there could be
// NaN and NaN*0 would poison protoc row 1399).
// ---------------------------------------------------------------------------
__global__ __launch_bounds__(256) void pe_k(float* __restrict__ pe,
                                            bf16* __restrict__ attn_tail) {
    int i = blockIdx.x * 256 + threadIdx.x;     // 0 .. 16383
    int s = i >> 11, d = i & 2047;
    float dv = expf((float)(d & ~1) * (-9.210340371976184f / 2048.0f));
    float ang = (float)s * dv;
    pe[i] = (d & 1) ? cosf(ang) * 0.1f : sinf(ang) * 0.1f;
    for (int j = i; j < 32 * ATT_STRIDE; j += 64 * 256) attn_tail[j] = f2bf(0.f);
}

// ---------------------------------------------------------------------------
// pexb[r][d] = fp32 src[n][s][d] + pe[s][d] -> bf16 (1800 rows, vectorized)
// ---------------------------------------------------------------------------
__global__ __launch_bounds__(256) void pex_k(const float* __restrict__ sup,
                                             const float* __restrict__ qry,
                                             const float* __restrict__ pe,
                                             bf16* __restrict__ pexb) {
    int r = blockIdx.x, t = threadIdx.x;
    int n, s;
    const float* src;
    if (r < 200) { n = r >> 3; s = r & 7; src = sup; }
    else { int rr = r - 200; n = rr >> 3; s = rr & 7; src = qry; }
    const float4* row = (const float4*)(src + ((size_t)n * SEQ + s) * DM);
    const float4* per = (const float4*)(pe + (size_t)s * DM);
    ushort4* orow = (ushort4*)(pexb + (size_t)r * DM);
    for (int d = t; d < DM / 4; d += 256) {
        float4 a = row[d], p = per[d];
        ushort4 o;
        o.x = f2bits(a.x + p.x); o.y = f2bits(a.y + p.y);
        o.z = f2bits(a.z + p.z); o.w = f2bits(a.w + p.w);
        orow[d] = o;
    }
}

// ---------------------------------------------------------------------------
// Generic MFMA bf16 GEMM: C = scale*A*B^T; z shifts A/B/C by aZ/bZ/cZ elems.
// EXACT revert to the proven-fastest schedule (74.8us on the projection):
// reg stage (uint4 x4) -> sync -> LDS write -> sync -> ds_read -> 16 MFMA,
// single LDS buffer; the compiler hoists next-iter global loads above the
// MFMA cluster (implicit 1-deep pipeline).  Every explicit rescheduling
// attempt lost: gload_lds 116/128us (forced vmcnt drain), 2-deep reg
// prefetch 86.5us (VGPR pressure), 1-barrier dbuf 85.2us, LDS-free 180us
// (16 far-apart cache lines per fragment load -> latency-bound).
// ONLY addition: bijective XCD-chunked block swizzle (proven FETCH 104->50MB
// on this op; ~10 SALU at entry).
// C rows >= mlim are not stored (M-pad garbage containment).
// ---------------------------------------------------------------------------
__global__ __launch_bounds__(256) void gemm_bt(
    const bf16* __restrict__ A, int lda, size_t aZ,
    const bf16* __restrict__ B, int ldb, size_t bZ,
    float scale, bf16* __restrict__ C, int ldc, size_t cZ, int K, int mlim) {
    // ---- XCD swizzle: logical tile id lg from hw block id (bijective) ----
    const int gx = gridDim.x, gy = gridDim.y;
    const int nwg = gx * gy * (int)gridDim.z;
    const int orig = ((int)blockIdx.z * gy + blockIdx.y) * gx + blockIdx.x;
    const int qc = nwg >> 3, rc = nwg & 7;
    const int xcd = orig & 7, sub = orig >> 3;
    const int lg = (xcd < rc ? xcd * (qc + 1) : rc * (qc + 1) + (xcd - rc) * qc) + sub;
    const int bx = lg % gx;
    const int rest = lg / gx;
    const int by = rest % gy, bz = rest / gy;

    const unsigned short* Ag0 = (const unsigned short*)A + aZ * bz;
    const unsigned short* Bg0 = (const unsigned short*)B + bZ * bz;
    const size_t cbase = cZ * bz;
    const int tile_m = bx * 128, tile_n = by * 128;
    __shared__ unsigned short As[4 * 128 * 8];
    __shared__ unsigned short Bs[4 * 128 * 8];
    const int t = threadIdx.x, lane = t & 63, wave = t >> 6;
    const int wm = (wave & 1) * 64, wn = (wave >> 1) * 64;
    const int srow = t >> 1, sq0 = (t & 1) * 2;
    const unsigned short* Ag = Ag0 + (size_t)(tile_m + srow) * lda + (t & 1) * 16;
    const unsigned short* Bg = Bg0 + (size_t)(tile_n + srow) * ldb + (t & 1) * 16;
    unsigned short* AsW0 = &As[((sq0 + 0) * 128 + srow) * 8];
    unsigned short* AsW1 = &As[((sq0 + 1) * 128 + srow) * 8];
    unsigned short* BsW0 = &Bs[((sq0 + 0) * 128 + srow) * 8];
    unsigned short* BsW1 = &Bs[((sq0 + 1) * 128 + srow) * 8];
    const int fr = lane & 15, quad = lane >> 4;

    f32x4 acc[4][4];
#pragma unroll
    for (int i = 0; i < 4; i++)
#pragma unroll
        for (int j = 0; j < 4; j++) acc[i][j] = {0.f, 0.f, 0.f, 0.f};

    for (int k0 = 0; k0 < K; k0 += 32) {
        uint4 a0 = *(const uint4*)(Ag + k0);
        uint4 a1 = *(const uint4*)(Ag + k0 + 8);
        uint4 b0 = *(const uint4*)(Bg + k0);
        uint4 b1 = *(const uint4*)(Bg + k0 + 8);
        __syncthreads();
        *(uint4*)AsW0 = a0; *(uint4*)AsW1 = a1;
        *(uint4*)BsW0 = b0; *(uint4*)BsW1 = b1;
        __syncthreads();
        s16x8 af[4], bfv[4];
#pragma unroll
        for (int i = 0; i < 4; i++)
            af[i] = *(const s16x8*)&As[(quad * 128 + wm + i * 16 + fr) * 8];
#pragma unroll
        for (int j = 0; j < 4; j++)
            bfv[j] = *(const s16x8*)&Bs[(quad * 128 + wn + j * 16 + fr) * 8];
#pragma unroll
        for (int i = 0; i < 4; i++)
#pragma unroll
            for (int j = 0; j < 4; j++)
                acc[i][j] = __builtin_amdgcn_mfma_f32_16x16x32_bf16(af[i], bfv[j], acc[i][j], 0, 0, 0);
    }

    const int rb = quad * 4;
#pragma unroll
    for (int i = 0; i < 4; i++)
#pragma unroll
        for (int j = 0; j < 4; j++) {
            const int col = tile_n + wn + j * 16 + fr;
#pragma unroll
            for (int r = 0; r < 4; r++) {
                const int row = tile_m + wm + i * 16 + rb + r;
                if (row < mlim)
                    C[cbase + (size_t)row * ldc + col] = f2bf(acc[i][j][r] * scale);
            }
        }
}

// ---------------------------------------------------------------------------
// combine_k: ks[m][n] = LN(Yk[ra][2n] + Yk[rb][2n+1] + kb[n])
// ---------------------------------------------------------------------------
__global__ __launch_bounds__(256) void combine_k(
    const unsigned int* __restrict__ Yk, const float* __restrict__ kb,
    const float* __restrict__ lng, const float* __restrict__ lnb,
    bf16* __restrict__ ks) {
    const int m = blockIdx.x, t = threadIdx.x, lane = t & 63, wave = t >> 6;
    int mm = m < 700 ? m : m - 700;
    int base = m < 700 ? 0 : 200;
    int nsamp = mm / LT, l = mm - nsamp * LT;
    const unsigned int* ya = Yk + (size_t)(base + nsamp * 8 + TUP_A[l]) * (N2 / 2);
    const unsigned int* yb = Yk + (size_t)(base + nsamp * 8 + TUP_B[l]) * (N2 / 2);
    float vals[5];
    int cnt = 0;
    float s = 0.f, s2 = 0.f;
    for (int n = t; n < OUTD; n += 256) {
        unsigned int ua = ya[n], ub = yb[n];
        float vk = ubits2f(ua & 0xFFFFu) + ubits2f(ub >> 16) + kb[n];
        vals[cnt++] = vk;
        s += vk; s2 += vk * vk;
    }
    for (int o = 32; o > 0; o >>= 1) { s += __shfl_xor(s, o); s2 += __shfl_xor(s2, o); }
    __shared__ float r1[4], r2[4];
    if (lane == 0) { r1[wave] = s; r2[wave] = s2; }
    __syncthreads();
    s = r1[0] + r1[1] + r1[2] + r1[3];
    s2 = r2[0] + r2[1] + r2[2] + r2[3];
    float mu = s * (1.f / OUTD);
    float var = s2 * (1.f / OUTD) - mu * mu;
    float inv = rsqrtf(fmaxf(var, 0.f) + 1e-5f);
    cnt = 0;
    for (int n = t; n < OUTD; n += 256)
        ks[(size_t)m * OUTD + n] = f2bf((vals[cnt++] - mu) * inv * lng[n] + lnb[n]);
}

// ---------------------------------------------------------------------------
// combine_v: vs[m][n] = Yv[ra][2n] + Yv[rb][2n+1] + vb[n]
// ---------------------------------------------------------------------------
__global__ __launch_bounds__(256) void combine_v(
    const unsigned int* __restrict__ Yv, const float* __restrict__ vb,
    bf16* __restrict__ vs) {
    const int m = blockIdx.x, t = threadIdx.x;
    int mm = m < 700 ? m : m - 700;
    int base = m < 700 ? 0 : 200;
    int nsamp = mm / LT, l = mm - nsamp * LT;
    const unsigned int* ya = Yv + (size_t)(base + nsamp * 8 + TUP_A[l]) * (N2 / 2);
    const unsigned int* yb = Yv + (size_t)(base + nsamp * 8 + TUP_B[l]) * (N2 / 2);
    for (int n = t; n < OUTD; n += 256) {
        unsigned int ua = ya[n], ub = yb[n];
        vs[(size_t)m * OUTD + n] =
            f2bf(ubits2f(ua & 0xFFFFu) + ubits2f(ub >> 16) + vb[n]);
    }
}

// ---------------------------------------------------------------------------
// softmax: one WAVE per (row, class): 140 = 64+64+12 elems/lane-slot; pure
// 64-lane shuffle reductions, ZERO barriers (was ~15 __syncthreads/block).
// attn laid out as 5 x 144-col blocks; cols 140..143 of each block zeroed.
// ---------------------------------------------------------------------------
__global__ __launch_bounds__(320) void softmax_k(const bf16* __restrict__ sc,
                                                 bf16* __restrict__ attn) {
    const int row = blockIdx.x, w = threadIdx.x >> 6, lane = threadIdx.x & 63;
    const bf16* src = sc + (size_t)row * SN_PAD + w * 140;
    bf16* dst = attn + (size_t)row * ATT_STRIDE + w * ABLK;
    float a = bf2f(src[lane]);
    float b = bf2f(src[lane + 64]);            // lane+64 <= 127 < 140: valid
    float c = (lane < 12) ? bf2f(src[lane + 128]) : -3.0e38f;
    float m = fmaxf(fmaxf(a, b), c);
    for (int o = 32; o > 0; o >>= 1) m = fmaxf(m, __shfl_xor(m, o));
    float ea = __expf(a - m), eb = __expf(b - m);
    float ec = (lane < 12) ? __expf(c - m) : 0.f;
    float s = ea + eb + ec;
    for (int o = 32; o > 0; o >>= 1) s += __shfl_xor(s, o);
    float inv = 1.f / s;
    dst[lane] = f2bf(ea * inv);
    dst[lane + 64] = f2bf(eb * inv);
    if (lane < 16) dst[lane + 128] = f2bf(lane < 12 ? ec * inv : 0.f);
}

// ---------------------------------------------------------------------------
// vsp[w][d][j] = vs[w*140+j][d] (j>=140 -> 0); block 0 also zeroes gbuf
// ---------------------------------------------------------------------------
__global__ __launch_bounds__(256) void vspad_k(const bf16* __restrict__ vs,
                                               bf16* __restrict__ vp,
                                               float* __restrict__ gbuf) {
    int idx = blockIdx.x * 256 + threadIdx.x;
    if (blockIdx.x == 0)
        for (int i = threadIdx.x; i < NQ * 21; i += 256) gbuf[i] = 0.f;
    if (idx >= 5 * OUTD * KP) return;
    int j = idx % KP;
    int rest = idx / KP;
    int dcol = rest % OUTD;
    int w = rest / OUTD;
    vp[idx] = (j < 140) ? vs[(size_t)(w * 140 + j) * OUTD + dcol] : f2bf(0.f);
}

// ---------------------------------------------------------------------------
// Gram reduce over a proto chunk -> 21 sufficient stats per query.
// Vectorized: s16x8 (16B) loads, 2 tuple-rows per block, grid (50,14).
// Rows are 1152 bf16 = 2304 B (16B-aligned), so 16B loads are safe.
// ---------------------------------------------------------------------------
__global__ __launch_bounds__(256) void gramred_k(const bf16* __restrict__ protoc,
                                                 const bf16* __restrict__ vs,
                                                 float* __restrict__ gbuf,
                                                 int row0, int q0) {
    const int ql = blockIdx.x;          // 0..49
    const int lgb = blockIdx.y;         // 0..13 (2 tuple-rows each)
    const int t = threadIdx.x, lane = t & 63, wave = t >> 6;
    const size_t PZ = (size_t)CH_MPAD * OUTD;
    float g[15] = {0.f};
    float h[5] = {0.f, 0.f, 0.f, 0.f, 0.f};
    float e = 0.f;
    for (int idx = t; idx < 2 * OUTD / 8; idx += 256) {   // 288 16B-slots
        int li = idx / 144;
        int dv = idx - li * 144;
        int l = lgb * 2 + li;
        size_t ml = (size_t)(ql * LT + l) * OUTD + dv * 8;
        s16x8 pw0 = *(const s16x8*)&protoc[0 * PZ + ml];
        s16x8 pw1 = *(const s16x8*)&protoc[1 * PZ + ml];
        s16x8 pw2 = *(const s16x8*)&protoc[2 * PZ + ml];
        s16x8 pw3 = *(const s16x8*)&protoc[3 * PZ + ml];
        s16x8 pw4 = *(const s16x8*)&protoc[4 * PZ + ml];
        s16x8 vv = *(const s16x8*)&vs[(size_t)(700 + row0 + ql * LT + l) * OUTD + dv * 8];
#pragma unroll
        for (int ee = 0; ee < 8; ee++) {
            float pv[5];
            pv[0] = ubits2f((unsigned short)pw0[ee]);
            pv[1] = ubits2f((unsigned short)pw1[ee]);
            pv[2] = ubits2f((unsigned short)pw2[ee]);
            pv[3] = ubits2f((unsigned short)pw3[ee]);
            pv[4] = ubits2f((unsigned short)pw4[ee]);
            float v = ubits2f((unsigned short)vv[ee]);
            e += v * v;
            int c = 0;
#pragma unroll
            for (int a = 0; a < 5; a++) {
                h[a] += v * pv[a];
#pragma unroll
                for (int b = a; b < 5; b++) g[c++] += pv[a] * pv[b];
            }
        }
    }
    float vals[21];
#pragma unroll
    for (int k = 0; k < 15; k++) vals[k] = g[k];
#pragma unroll
    for (int k = 0; k < 5; k++) vals[15 + k] = h[k];
    vals[20] = e;
#pragma unroll
    for (int k = 0; k < 21; k++)
        for (int o = 32; o > 0; o >>= 1) vals[k] += __shfl_xor(vals[k], o);
    __shared__ float red[4][21];
    if (lane == 0)
#pragma unroll
        for (int k = 0; k < 21; k++) red[wave][k] = vals[k];
    __syncthreads();
    if (t < 21) {
        float s = red[0][t] + red[1][t] + red[2][t] + red[3][t];
        atomicAdd(&gbuf[(q0 + ql) * 21 + t], s);
    }
}

// ---------------------------------------------------------------------------
// out (fp32): per q -> 25 sim + 5 ori
// ---------------------------------------------------------------------------
__global__ __launch_bounds__(64) void out_k(const float* __restrict__ gbuf,
                                            float* __restrict__ out) {
    int q = blockIdx.x;
    if (threadIdx.x != 0) return;
    const float* r = gbuf + q * 21;
    float G[5][5];
    int c = 0;
    for (int a = 0; a < 5; a++)
        for (int b = a; b < 5; b++) { G[a][b] = r[c]; G[b][a] = r[c]; c++; }
    float e = r[20];
    float nrm[5];
    for (int a = 0; a < 5; a++) nrm[a] = sqrtf(fmaxf(G[a][a], 0.f));
    for (int a = 0; a < 5; a++)
        for (int b = 0; b < 5; b++)
            out[(size_t)q * 25 + a * 5 + b] = G[a][b] / fmaxf(nrm[a] * nrm[b], 1e-8f);
    for (int w = 0; w < 5; w++)
        out[5000 + (size_t)q * 5 + w] = -(e - 2.f * r[15 + w] + G[w][w]) * (1.f / 28.f);
}

// ---------------------------------------------------------------------------
extern "C" void kernel_launch(void* const* d_in, const int* in_sizes, int n_in,
                              void* d_out, int out_size, void* d_ws, size_t ws_size,
                              hipStream_t stream) {
    const float* sup = (const float*)d_in[0];
    // d_in[1] = support_labels int32 — unused (sorted equal-shot)
    const float* qry = (const float*)d_in[2];
    const float* k_w = (const float*)d_in[3];
    const float* k_b = (const float*)d_in[4];
    const float* v_w = (const float*)d_in[5];
    const float* v_b = (const float*)d_in[6];
    const float* lng = (const float*)d_in[7];
    const float* lnb = (const float*)d_in[8];
    (void)in_sizes; (void)n_in; (void)out_size; (void)ws_size;

    // layout (bytes), peak 49,421,728 (<= verified ws_size >= 54.5 MB):
    //   pexb   @0           7,864,320 (1920 rows; 1800 real)  dead after proj
    //   wbf    @7,864,320  18,874,368 (k|v bf16)              dead after proj
    //   Yk     @26,738,688  8,294,400 (1800x2304)             dead after comb_k
    //   Yv     @35,033,088  8,294,400                         dead after comb_v
    //   ks     @0          14,588,928 (6332 rows; 6300 real)  dead after scores
    //   vs     @16,220,160 14,515,200 (6300 rows)             live to end
    //   sc     @30,735,360  8,650,752 (over dead Yk/Yv head)  dead after softmax
    //   vsp    @39,386,112  1,843,200
    //   attn   @41,229,312  8,110,080 (5632 rows x 720; 5 x 144-col blocks)
    //   gbuf   @49,339,392     16,800
    //   pe     @49,356,192     65,536 (8x2048 fp32 table)
    //   protoc @0          16,220,160 (over dead ks, after scores)
    char* ws = (char*)d_ws;
    bf16* pexb   = (bf16*)(ws + 0);
    bf16* wbf    = (bf16*)(ws + 7864320);
    bf16* Yk     = (bf16*)(ws + 26738688);
    bf16* Yv     = (bf16*)(ws + 35033088);
    bf16* ks     = (bf16*)(ws + 0);
    bf16* vs     = (bf16*)(ws + 16220160);
    bf16* sc     = (bf16*)(ws + 30735360);
    bf16* vsp    = (bf16*)(ws + 39386112);
    bf16* attn   = (bf16*)(ws + 41229312);
    float* gbuf  = (float*)(ws + 49339392);
    float* pe    = (float*)(ws + 49356192);
    bf16* protoc = (bf16*)(ws + 0);

    pe_k<<<dim3(64), dim3(256), 0, stream>>>(pe, attn + (size_t)SM * ATT_STRIDE);
    pex_k<<<dim3(1800), dim3(256), 0, stream>>>(sup, qry, pe, pexb);
    wconv2_k<<<dim3(9216), dim3(256), 0, stream>>>(
        (const float4*)k_w, (const float4*)v_w, (ushort4*)wbf);

    // fused K+V projection: z in {k,v}; Y[1800,2304] = pexb @ W_view^T
    gemm_bt<<<dim3(15, 18, 2), dim3(256), 0, stream>>>(
        pexb, DM, 0, wbf, DM, (size_t)4718592,
        1.0f, Yk, N2, (size_t)4147200, DM, 1800);

    combine_k<<<dim3(M_ALL), dim3(256), 0, stream>>>(
        (const unsigned int*)Yk, k_b, lng, lnb, ks);
    combine_v<<<dim3(M_ALL), dim3(256), 0, stream>>>(
        (const unsigned int*)Yv, v_b, vs);

    // scores: ks_q[5632,1152] @ ks_s[768,1152]^T / sqrt(1152)
    gemm_bt<<<dim3(44, 6, 1), dim3(256), 0, stream>>>(
        ks + (size_t)700 * OUTD, OUTD, 0, ks, OUTD, 0,
        0.029462782549439484f, sc, SN_PAD, 0, OUTD, 5632);

    vspad_k<<<dim3((5 * OUTD * KP + 255) / 256), dim3(256), 0, stream>>>(
        vs, vsp, gbuf);
    softmax_k<<<dim3(SM), dim3(320), 0, stream>>>(sc, attn);

    // proto chunks: 4 x 50 queries; per-class GEMM then Gram reduce
    // A = attn with 144-col class blocks (aZ=144, 16B-aligned); K=160 reads
    // spill 16 cols into the next block where vsp's zero columns kill them.
    for (int c = 0; c < 4; c++) {
        gemm_bt<<<dim3(11, 9, 5), dim3(256), 0, stream>>>(
            attn + (size_t)c * CH_ROWS * ATT_STRIDE, ATT_STRIDE, (size_t)ABLK,
            vsp, KP, (size_t)OUTD * KP,
            1.0f, protoc, OUTD, (size_t)CH_MPAD * OUTD, KP, CH_MPAD);
        gramred_k<<<dim3(CH_Q, 14), dim3(256), 0, stream>>>(
            protoc, vs, gbuf, c * CH_ROWS, c * CH_Q);
    }

    out_k<<<dim3(NQ), dim3(64), 0, stream>>>(gbuf, (float*)d_out);
}

// Round 8
// 334.795 us; speedup vs baseline: 1.4400x; 1.0129x over previous
//
#include <hip/hip_runtime.h>
#include <hip/hip_bf16.h>
#include <math.h>

typedef __hip_bfloat16 bf16;
typedef short s16x8 __attribute__((ext_vector_type(8)));
typedef float f32x4 __attribute__((ext_vector_type(4)));

#define NQ 200
#define SEQ 8
#define DM 2048
#define OUTD 1152
#define LT 28
#define M_ALL 6300
#define SM 5600
#define SN_PAD 768
#define ATT_STRIDE 720
#define N2 2304          // W viewed as [2304, 2048]
#define KP 160
#define CH_Q 50
#define CH_ROWS 1400
#define CH_MPAD 1408
#define ABLK 144         // attn per-class column block (16B-aligned)

__device__ __forceinline__ float bf2f(bf16 v) { return __bfloat162float(v); }
__device__ __forceinline__ bf16 f2bf(float v) { return __float2bfloat16(v); }
__device__ __forceinline__ float ubits2f(unsigned int u16) {
    unsigned int i = u16 << 16;
    float f; __builtin_memcpy(&f, &i, 4); return f;
}
__device__ __forceinline__ unsigned short f2bits(float f) {
    bf16 b = __float2bfloat16(f);
    unsigned short u; __builtin_memcpy(&u, &b, 2); return u;
}

__device__ const int TUP_A[LT] = {0,0,0,0,0,0,0,1,1,1,1,1,1,2,2,2,2,2,3,3,3,3,4,4,4,5,5,6};
__device__ const int TUP_B[LT] = {1,2,3,4,5,6,7,2,3,4,5,6,7,3,4,5,6,7,4,5,6,7,5,6,7,6,7,7};

// ---------------------------------------------------------------------------
// fused weight convert: [k_w | v_w] fp32 -> bf16 (2 x 1,179,648 float4)
// ---------------------------------------------------------------------------
__global__ __launch_bounds__(256) void wconv2_k(const float4* __restrict__ kw,
                                                const float4* __restrict__ vw,
                                                ushort4* __restrict__ o) {
    int i = blockIdx.x * 256 + threadIdx.x;     // 0 .. 2,359,295
    float4 v = (i < 1179648) ? kw[i] : vw[i - 1179648];
    ushort4 r;
    r.x = f2bits(v.x); r.y = f2bits(v.y); r.z = f2bits(v.z); r.w = f2bits(v.w);
    o[i] = r;
}

// ---------------------------------------------------------------------------
// pe table: pe[s][d], 8 x 2048 fp32 (trig computed once, not 1800x).
// Also zeroes attn tail rows 5600..5631 (never written by softmax; the proto
// GEMM's K-spill reads next-row cols 0..15, so uninit bf16 there could be
// NaN and NaN*0 would poison protoc row 1399).
// ---------------------------------------------------------------------------
__global__ __launch_bounds__(256) void pe_k(float* __restrict__ pe,
                                            bf16* __restrict__ attn_tail) {
    int i = blockIdx.x * 256 + threadIdx.x;     // 0 .. 16383
    int s = i >> 11, d = i & 2047;
    float dv = expf((float)(d & ~1) * (-9.210340371976184f / 2048.0f));
    float ang = (float)s * dv;
    pe[i] = (d & 1) ? cosf(ang) * 0.1f : sinf(ang) * 0.1f;
    for (int j = i; j < 32 * ATT_STRIDE; j += 64 * 256) attn_tail[j] = f2bf(0.f);
}

// ---------------------------------------------------------------------------
// pexb[r][d] = fp32 src[n][s][d] + pe[s][d] -> bf16 (1800 rows, vectorized)
// ---------------------------------------------------------------------------
__global__ __launch_bounds__(256) void pex_k(const float* __restrict__ sup,
                                             const float* __restrict__ qry,
                                             const float* __restrict__ pe,
                                             bf16* __restrict__ pexb) {
    int r = blockIdx.x, t = threadIdx.x;
    int n, s;
    const float* src;
    if (r < 200) { n = r >> 3; s = r & 7; src = sup; }
    else { int rr = r - 200; n = rr >> 3; s = rr & 7; src = qry; }
    const float4* row = (const float4*)(src + ((size_t)n * SEQ + s) * DM);
    const float4* per = (const float4*)(pe + (size_t)s * DM);
    ushort4* orow = (ushort4*)(pexb + (size_t)r * DM);
    for (int d = t; d < DM / 4; d += 256) {
        float4 a = row[d], p = per[d];
        ushort4 o;
        o.x = f2bits(a.x + p.x); o.y = f2bits(a.y + p.y);
        o.z = f2bits(a.z + p.z); o.w = f2bits(a.w + p.w);
        orow[d] = o;
    }
}

// ---------------------------------------------------------------------------
// Generic MFMA bf16 GEMM: C = scale*A*B^T; z shifts A/B/C by aZ/bZ/cZ elems.
// Proven-fastest schedule (round-6: 71.7us): reg stage -> sync -> LDS write
// -> sync -> ds_read -> MFMA, single LDS buffer (compiler gives implicit
// 1-deep pipeline).  All explicit rescheduling lost (gload_lds 116/128us,
// 2-deep 86.5us, 1-barrier dbuf 85.2us, LDS-free 180us).
// NEW: templated N-tile.  TN=64 doubles the grid (128x64 tiles) to raise
// blocks/CU ~1.5->3-4: round-6 counters showed Occupancy 19% (grid-limited,
// resources allow ~7 blocks/CU) -> barrier drains latency-exposed.
// K-accumulation order per output unchanged -> bitwise-identical C.
// XCD-chunked bijective block swizzle kept (FETCH 104->42 MB measured).
// C rows >= mlim are not stored (M-pad garbage containment).
// ---------------------------------------------------------------------------
template <int TN>
__global__ __launch_bounds__(256) void gemm_bt(
    const bf16* __restrict__ A, int lda, size_t aZ,
    const bf16* __restrict__ B, int ldb, size_t bZ,
    float scale, bf16* __restrict__ C, int ldc, size_t cZ, int K, int mlim) {
    constexpr int JN = TN / 32;            // B-frags per wave (2 or 4)
    // ---- XCD swizzle: logical tile id lg from hw block id (bijective) ----
    const int gx = gridDim.x, gy = gridDim.y;
    const int nwg = gx * gy * (int)gridDim.z;
    const int orig = ((int)blockIdx.z * gy + blockIdx.y) * gx + blockIdx.x;
    const int qc = nwg >> 3, rc = nwg & 7;
    const int xcd = orig & 7, sub = orig >> 3;
    const int lg = (xcd < rc ? xcd * (qc + 1) : rc * (qc + 1) + (xcd - rc) * qc) + sub;
    const int bx = lg % gx;
    const int rest = lg / gx;
    const int by = rest % gy, bz = rest / gy;

    const unsigned short* Ag0 = (const unsigned short*)A + aZ * bz;
    const unsigned short* Bg0 = (const unsigned short*)B + bZ * bz;
    const size_t cbase = cZ * bz;
    const int tile_m = bx * 128, tile_n = by * TN;
    __shared__ unsigned short As[4 * 128 * 8];
    __shared__ unsigned short Bs[4 * TN * 8];
    const int t = threadIdx.x, lane = t & 63, wave = t >> 6;
    const int wm = (wave & 1) * 64, wn = (wave >> 1) * (TN / 2);
    const int srow = t >> 1, sq0 = (t & 1) * 2;
    const unsigned short* Ag = Ag0 + (size_t)(tile_m + srow) * lda + (t & 1) * 16;
    unsigned short* AsW0 = &As[((sq0 + 0) * 128 + srow) * 8];
    unsigned short* AsW1 = &As[((sq0 + 1) * 128 + srow) * 8];
    const unsigned short* Bg;
    unsigned short* BsW0;
    unsigned short* BsW1 = nullptr;
    if constexpr (TN == 128) {             // 128 rows x 4 kq: 2 uint4/thread
        Bg = Bg0 + (size_t)(tile_n + srow) * ldb + (t & 1) * 16;
        BsW0 = &Bs[((sq0 + 0) * 128 + srow) * 8];
        BsW1 = &Bs[((sq0 + 1) * 128 + srow) * 8];
    } else {                               // 64 rows x 4 kq: 1 uint4/thread
        Bg = Bg0 + (size_t)(tile_n + (t >> 2)) * ldb + (t & 3) * 8;
        BsW0 = &Bs[((t & 3) * 64 + (t >> 2)) * 8];
    }
    const int fr = lane & 15, quad = lane >> 4;

    f32x4 acc[4][JN];
#pragma unroll
    for (int i = 0; i < 4; i++)
#pragma unroll
        for (int j = 0; j < JN; j++) acc[i][j] = {0.f, 0.f, 0.f, 0.f};

    for (int k0 = 0; k0 < K; k0 += 32) {
        uint4 a0 = *(const uint4*)(Ag + k0);
        uint4 a1 = *(const uint4*)(Ag + k0 + 8);
        uint4 b0 = *(const uint4*)(Bg + k0);
        uint4 b1;
        if constexpr (TN == 128) b1 = *(const uint4*)(Bg + k0 + 8);
        __syncthreads();
        *(uint4*)AsW0 = a0; *(uint4*)AsW1 = a1;
        *(uint4*)BsW0 = b0;
        if constexpr (TN == 128) *(uint4*)BsW1 = b1;
        __syncthreads();
        s16x8 af[4], bfv[JN];
#pragma unroll
        for (int i = 0; i < 4; i++)
            af[i] = *(const s16x8*)&As[(quad * 128 + wm + i * 16 + fr) * 8];
#pragma unroll
        for (int j = 0; j < JN; j++)
            bfv[j] = *(const s16x8*)&Bs[(quad * TN + wn + j * 16 + fr) * 8];
#pragma unroll
        for (int i = 0; i < 4; i++)
#pragma unroll
            for (int j = 0; j < JN; j++)
                acc[i][j] = __builtin_amdgcn_mfma_f32_16x16x32_bf16(af[i], bfv[j], acc[i][j], 0, 0, 0);
    }

    const int rb = quad * 4;
#pragma unroll
    for (int i = 0; i < 4; i++)
#pragma unroll
        for (int j = 0; j < JN; j++) {
            const int col = tile_n + wn + j * 16 + fr;
#pragma unroll
            for (int r = 0; r < 4; r++) {
                const int row = tile_m + wm + i * 16 + rb + r;
                if (row < mlim)
                    C[cbase + (size_t)row * ldc + col] = f2bf(acc[i][j][r] * scale);
            }
        }
}

// ---------------------------------------------------------------------------
// combine_kv (merged, one launch): blocks [0,M_ALL) do the K path (LN),
// blocks [M_ALL, 2*M_ALL) do the V path.  Math identical to the split
// kernels (round-4-verified).
// ---------------------------------------------------------------------------
__global__ __launch_bounds__(256) void combine_kv(
    const unsigned int* __restrict__ Yk, const unsigned int* __restrict__ Yv,
    const float* __restrict__ kb, const float* __restrict__ vb,
    const float* __restrict__ lng, const float* __restrict__ lnb,
    bf16* __restrict__ ks, bf16* __restrict__ vs) {
    const int t = threadIdx.x, lane = t & 63, wave = t >> 6;
    int m = blockIdx.x;
    const bool vpath = m >= M_ALL;
    if (vpath) m -= M_ALL;
    int mm = m < 700 ? m : m - 700;
    int base = m < 700 ? 0 : 200;
    int nsamp = mm / LT, l = mm - nsamp * LT;
    const unsigned int* Y = vpath ? Yv : Yk;
    const unsigned int* ya = Y + (size_t)(base + nsamp * 8 + TUP_A[l]) * (N2 / 2);
    const unsigned int* yb = Y + (size_t)(base + nsamp * 8 + TUP_B[l]) * (N2 / 2);
    if (vpath) {
        for (int n = t; n < OUTD; n += 256) {
            unsigned int ua = ya[n], ub = yb[n];
            vs[(size_t)m * OUTD + n] =
                f2bf(ubits2f(ua & 0xFFFFu) + ubits2f(ub >> 16) + vb[n]);
        }
        return;
    }
    float vals[5];
    int cnt = 0;
    float s = 0.f, s2 = 0.f;
    for (int n = t; n < OUTD; n += 256) {
        unsigned int ua = ya[n], ub = yb[n];
        float vk = ubits2f(ua & 0xFFFFu) + ubits2f(ub >> 16) + kb[n];
        vals[cnt++] = vk;
        s += vk; s2 += vk * vk;
    }
    for (int o = 32; o > 0; o >>= 1) { s += __shfl_xor(s, o); s2 += __shfl_xor(s2, o); }
    __shared__ float r1[4], r2[4];
    if (lane == 0) { r1[wave] = s; r2[wave] = s2; }
    __syncthreads();
    s = r1[0] + r1[1] + r1[2] + r1[3];
    s2 = r2[0] + r2[1] + r2[2] + r2[3];
    float mu = s * (1.f / OUTD);
    float var = s2 * (1.f / OUTD) - mu * mu;
    float inv = rsqrtf(fmaxf(var, 0.f) + 1e-5f);
    cnt = 0;
    for (int n = t; n < OUTD; n += 256)
        ks[(size_t)m * OUTD + n] = f2bf((vals[cnt++] - mu) * inv * lng[n] + lnb[n]);
}

// ---------------------------------------------------------------------------
// sv_k (merged softmax + vspad, one launch, 320 threads):
//  blocks [0,SM): softmax, one WAVE per (row, class), barrier-free
//    (140 = 64+64+12 lane-slots; attn as 5 x 144-col blocks, pad zeroed).
//  blocks [SM, SM+2880): vsp[w][d][j] = vs[w*140+j][d] (j>=140 -> 0);
//    block SM also zeroes gbuf.  2880*320 == 5*OUTD*KP exactly.
// ---------------------------------------------------------------------------
__global__ __launch_bounds__(320) void sv_k(const bf16* __restrict__ sc,
                                            bf16* __restrict__ attn,
                                            const bf16* __restrict__ vs,
                                            bf16* __restrict__ vp,
                                            float* __restrict__ gbuf) {
    const int t = threadIdx.x;
    if (blockIdx.x < SM) {
        const int row = blockIdx.x, w = t >> 6, lane = t & 63;
        const bf16* src = sc + (size_t)row * SN_PAD + w * 140;
        bf16* dst = attn + (size_t)row * ATT_STRIDE + w * ABLK;
        float a = bf2f(src[lane]);
        float b = bf2f(src[lane + 64]);        // lane+64 <= 127 < 140: valid
        float c = (lane < 12) ? bf2f(src[lane + 128]) : -3.0e38f;
        float m = fmaxf(fmaxf(a, b), c);
        for (int o = 32; o > 0; o >>= 1) m = fmaxf(m, __shfl_xor(m, o));
        float ea = __expf(a - m), eb = __expf(b - m);
        float ec = (lane < 12) ? __expf(c - m) : 0.f;
        float s = ea + eb + ec;
        for (int o = 32; o > 0; o >>= 1) s += __shfl_xor(s, o);
        float inv = 1.f / s;
        dst[lane] = f2bf(ea * inv);
        dst[lane + 64] = f2bf(eb * inv);
        if (lane < 16) dst[lane + 128] = f2bf(lane < 12 ? ec * inv : 0.f);
        return;
    }
    const int vb = blockIdx.x - SM;            // 0..2879
    if (vb == 0)
        for (int i = t; i < NQ * 21; i += 320) gbuf[i] = 0.f;
    int idx = vb * 320 + t;                    // < 921600 == 5*OUTD*KP
    int j = idx % KP;
    int rest = idx / KP;
    int dcol = rest % OUTD;
    int w = rest / OUTD;
    vp[idx] = (j < 140) ? vs[(size_t)(w * 140 + j) * OUTD + dcol] : f2bf(0.f);
}

// ---------------------------------------------------------------------------
// Gram reduce over a proto chunk -> 21 sufficient stats per query.
// Vectorized: s16x8 (16B) loads, 2 tuple-rows per block, grid (50,14).
// Rows are 1152 bf16 = 2304 B (16B-aligned), so 16B loads are safe.
// ---------------------------------------------------------------------------
__global__ __launch_bounds__(256) void gramred_k(const bf16* __restrict__ protoc,
                                                 const bf16* __restrict__ vs,
                                                 float* __restrict__ gbuf,
                                                 int row0, int q0) {
    const int ql = blockIdx.x;          // 0..49
    const int lgb = blockIdx.y;         // 0..13 (2 tuple-rows each)
    const int t = threadIdx.x, lane = t & 63, wave = t >> 6;
    const size_t PZ = (size_t)CH_MPAD * OUTD;
    float g[15] = {0.f};
    float h[5] = {0.f, 0.f, 0.f, 0.f, 0.f};
    float e = 0.f;
    for (int idx = t; idx < 2 * OUTD / 8; idx += 256) {   // 288 16B-slots
        int li = idx / 144;
        int dv = idx - li * 144;
        int l = lgb * 2 + li;
        size_t ml = (size_t)(ql * LT + l) * OUTD + dv * 8;
        s16x8 pw0 = *(const s16x8*)&protoc[0 * PZ + ml];
        s16x8 pw1 = *(const s16x8*)&protoc[1 * PZ + ml];
        s16x8 pw2 = *(const s16x8*)&protoc[2 * PZ + ml];
        s16x8 pw3 = *(const s16x8*)&protoc[3 * PZ + ml];
        s16x8 pw4 = *(const s16x8*)&protoc[4 * PZ + ml];
        s16x8 vv = *(const s16x8*)&vs[(size_t)(700 + row0 + ql * LT + l) * OUTD + dv * 8];
#pragma unroll
        for (int ee = 0; ee < 8; ee++) {
            float pv[5];
            pv[0] = ubits2f((unsigned short)pw0[ee]);
            pv[1] = ubits2f((unsigned short)pw1[ee]);
            pv[2] = ubits2f((unsigned short)pw2[ee]);
            pv[3] = ubits2f((unsigned short)pw3[ee]);
            pv[4] = ubits2f((unsigned short)pw4[ee]);
            float v = ubits2f((unsigned short)vv[ee]);
            e += v * v;
            int c = 0;
#pragma unroll
            for (int a = 0; a < 5; a++) {
                h[a] += v * pv[a];
#pragma unroll
                for (int b = a; b < 5; b++) g[c++] += pv[a] * pv[b];
            }
        }
    }
    float vals[21];
#pragma unroll
    for (int k = 0; k < 15; k++) vals[k] = g[k];
#pragma unroll
    for (int k = 0; k < 5; k++) vals[15 + k] = h[k];
    vals[20] = e;
#pragma unroll
    for (int k = 0; k < 21; k++)
        for (int o = 32; o > 0; o >>= 1) vals[k] += __shfl_xor(vals[k], o);
    __shared__ float red[4][21];
    if (lane == 0)
#pragma unroll
        for (int k = 0; k < 21; k++) red[wave][k] = vals[k];
    __syncthreads();
    if (t < 21) {
        float s = red[0][t] + red[1][t] + red[2][t] + red[3][t];
        atomicAdd(&gbuf[(q0 + ql) * 21 + t], s);
    }
}

// ---------------------------------------------------------------------------
// out (fp32): per q -> 25 sim + 5 ori
// ---------------------------------------------------------------------------
__global__ __launch_bounds__(64) void out_k(const float* __restrict__ gbuf,
                                            float* __restrict__ out) {
    int q = blockIdx.x;
    if (threadIdx.x != 0) return;
    const float* r = gbuf + q * 21;
    float G[5][5];
    int c = 0;
    for (int a = 0; a < 5; a++)
        for (int b = a; b < 5; b++) { G[a][b] = r[c]; G[b][a] = r[c]; c++; }
    float e = r[20];
    float nrm[5];
    for (int a = 0; a < 5; a++) nrm[a] = sqrtf(fmaxf(G[a][a], 0.f));
    for (int a = 0; a < 5; a++)
        for (int b = 0; b < 5; b++)
            out[(size_t)q * 25 + a * 5 + b] = G[a][b] / fmaxf(nrm[a] * nrm[b], 1e-8f);
    for (int w = 0; w < 5; w++)
        out[5000 + (size_t)q * 5 + w] = -(e - 2.f * r[15 + w] + G[w][w]) * (1.f / 28.f);
}

// ---------------------------------------------------------------------------
extern "C" void kernel_launch(void* const* d_in, const int* in_sizes, int n_in,
                              void* d_out, int out_size, void* d_ws, size_t ws_size,
                              hipStream_t stream) {
    const float* sup = (const float*)d_in[0];
    // d_in[1] = support_labels int32 — unused (sorted equal-shot)
    const float* qry = (const float*)d_in[2];
    const float* k_w = (const float*)d_in[3];
    const float* k_b = (const float*)d_in[4];
    const float* v_w = (const float*)d_in[5];
    const float* v_b = (const float*)d_in[6];
    const float* lng = (const float*)d_in[7];
    const float* lnb = (const float*)d_in[8];
    (void)in_sizes; (void)n_in; (void)out_size; (void)ws_size;

    // layout (bytes), peak 49,421,728 (<= verified ws_size >= 54.5 MB):
    //   pexb   @0           7,864,320 (1920 rows; 1800 real)  dead after proj
    //   wbf    @7,864,320  18,874,368 (k|v bf16)              dead after proj
    //   Yk     @26,738,688  8,294,400 (1800x2304)             dead after comb_k
    //   Yv     @35,033,088  8,294,400                         dead after comb_v
    //   ks     @0          14,588,928 (6332 rows; 6300 real)  dead after scores
    //   vs     @16,220,160 14,515,200 (6300 rows)             live to end
    //   sc     @30,735,360  8,650,752 (over dead Yk/Yv head)  dead after softmax
    //   vsp    @39,386,112  1,843,200
    //   attn   @41,229,312  8,110,080 (5632 rows x 720; 5 x 144-col blocks)
    //   gbuf   @49,339,392     16,800
    //   pe     @49,356,192     65,536 (8x2048 fp32 table)
    //   protoc @0          16,220,160 (over dead ks, after scores)
    char* ws = (char*)d_ws;
    bf16* pexb   = (bf16*)(ws + 0);
    bf16* wbf    = (bf16*)(ws + 7864320);
    bf16* Yk     = (bf16*)(ws + 26738688);
    bf16* Yv     = (bf16*)(ws + 35033088);
    bf16* ks     = (bf16*)(ws + 0);
    bf16* vs     = (bf16*)(ws + 16220160);
    bf16* sc     = (bf16*)(ws + 30735360);
    bf16* vsp    = (bf16*)(ws + 39386112);
    bf16* attn   = (bf16*)(ws + 41229312);
    float* gbuf  = (float*)(ws + 49339392);
    float* pe    = (float*)(ws + 49356192);
    bf16* protoc = (bf16*)(ws + 0);

    pe_k<<<dim3(64), dim3(256), 0, stream>>>(pe, attn + (size_t)SM * ATT_STRIDE);
    pex_k<<<dim3(1800), dim3(256), 0, stream>>>(sup, qry, pe, pexb);
    wconv2_k<<<dim3(9216), dim3(256), 0, stream>>>(
        (const float4*)k_w, (const float4*)v_w, (ushort4*)wbf);

    // fused K+V projection: z in {k,v}; Y[1800,2304] = pexb @ W_view^T
    gemm_bt<64><<<dim3(15, 36, 2), dim3(256), 0, stream>>>(
        pexb, DM, 0, wbf, DM, (size_t)4718592,
        1.0f, Yk, N2, (size_t)4147200, DM, 1800);

    combine_kv<<<dim3(2 * M_ALL), dim3(256), 0, stream>>>(
        (const unsigned int*)Yk, (const unsigned int*)Yv,
        k_b, v_b, lng, lnb, ks, vs);

    // scores: ks_q[5632,1152] @ ks_s[768,1152]^T / sqrt(1152)
    gemm_bt<64><<<dim3(44, 12, 1), dim3(256), 0, stream>>>(
        ks + (size_t)700 * OUTD, OUTD, 0, ks, OUTD, 0,
        0.029462782549439484f, sc, SN_PAD, 0, OUTD, 5632);

    // merged softmax (5600 blocks) + vspad (2880 blocks), 320 threads
    sv_k<<<dim3(SM + 2880), dim3(320), 0, stream>>>(sc, attn, vs, vsp, gbuf);

    // proto chunks: 4 x 50 queries; per-class GEMM then Gram reduce
    // A = attn with 144-col class blocks (aZ=144, 16B-aligned); K=160 reads
    // spill 16 cols into the next block where vsp's zero columns kill them.
    for (int c = 0; c < 4; c++) {
        gemm_bt<64><<<dim3(11, 18, 5), dim3(256), 0, stream>>>(
            attn + (size_t)c * CH_ROWS * ATT_STRIDE, ATT_STRIDE, (size_t)ABLK,
            vsp, KP, (size_t)OUTD * KP,
            1.0f, protoc, OUTD, (size_t)CH_MPAD * OUTD, KP, CH_MPAD);
        gramred_k<<<dim3(CH_Q, 14), dim3(256), 0, stream>>>(
            protoc, vs, gbuf, c * CH_ROWS, c * CH_Q);
    }

    out_k<<<dim3(NQ), dim3(64), 0, stream>>>(gbuf, (float*)d_out);
}

// Round 9
// 326.827 us; speedup vs baseline: 1.4751x; 1.0244x over previous
//
#include <hip/hip_runtime.h>
#include <hip/hip_bf16.h>
#include <math.h>

typedef __hip_bfloat16 bf16;
typedef short s16x8 __attribute__((ext_vector_type(8)));
typedef float f32x4 __attribute__((ext_vector_type(4)));

#define NQ 200
#define SEQ 8
#define DM 2048
#define OUTD 1152
#define LT 28
#define M_ALL 6300
#define SM 5600
#define SN_PAD 768
#define ATT_STRIDE 720
#define N2 2304          // W viewed as [2304, 2048]
#define KP 160
#define CH_Q 50
#define CH_ROWS 1400
#define CH_MPAD 1408
#define ABLK 144         // attn per-class column block (16B-aligned)

__device__ __forceinline__ float bf2f(bf16 v) { return __bfloat162float(v); }
__device__ __forceinline__ bf16 f2bf(float v) { return __float2bfloat16(v); }
__device__ __forceinline__ float ubits2f(unsigned int u16) {
    unsigned int i = u16 << 16;
    float f; __builtin_memcpy(&f, &i, 4); return f;
}
__device__ __forceinline__ unsigned short f2bits(float f) {
    bf16 b = __float2bfloat16(f);
    unsigned short u; __builtin_memcpy(&u, &b, 2); return u;
}

__device__ const int TUP_A[LT] = {0,0,0,0,0,0,0,1,1,1,1,1,1,2,2,2,2,2,3,3,3,3,4,4,4,5,5,6};
__device__ const int TUP_B[LT] = {1,2,3,4,5,6,7,2,3,4,5,6,7,3,4,5,6,7,4,5,6,7,5,6,7,6,7,7};

// ---------------------------------------------------------------------------
// fused weight convert: [k_w | v_w] fp32 -> bf16 (2 x 1,179,648 float4)
// ---------------------------------------------------------------------------
__global__ __launch_bounds__(256) void wconv2_k(const float4* __restrict__ kw,
                                                const float4* __restrict__ vw,
                                                ushort4* __restrict__ o) {
    int i = blockIdx.x * 256 + threadIdx.x;     // 0 .. 2,359,295
    float4 v = (i < 1179648) ? kw[i] : vw[i - 1179648];
    ushort4 r;
    r.x = f2bits(v.x); r.y = f2bits(v.y); r.z = f2bits(v.z); r.w = f2bits(v.w);
    o[i] = r;
}

// ---------------------------------------------------------------------------
// pe table: pe[s][d], 8 x 2048 fp32 (trig computed once, not 1800x).
// Also zeroes attn tail rows 5600..5631 (never written by softmax; the proto
// GEMM's K-spill reads next-row cols 0..15, so uninit bf16 there could be
// NaN and NaN*0 would poison protoc row 1399).
// ---------------------------------------------------------------------------
__global__ __launch_bounds__(256) void pe_k(float* __restrict__ pe,
                                            bf16* __restrict__ attn_tail) {
    int i = blockIdx.x * 256 + threadIdx.x;     // 0 .. 16383
    int s = i >> 11, d = i & 2047;
    float dv = expf((float)(d & ~1) * (-9.210340371976184f / 2048.0f));
    float ang = (float)s * dv;
    pe[i] = (d & 1) ? cosf(ang) * 0.1f : sinf(ang) * 0.1f;
    for (int j = i; j < 32 * ATT_STRIDE; j += 64 * 256) attn_tail[j] = f2bf(0.f);
}

// ---------------------------------------------------------------------------
// pexb[r][d] = fp32 src[n][s][d] + pe[s][d] -> bf16 (1800 rows, vectorized)
// ---------------------------------------------------------------------------
__global__ __launch_bounds__(256) void pex_k(const float* __restrict__ sup,
                                             const float* __restrict__ qry,
                                             const float* __restrict__ pe,
                                             bf16* __restrict__ pexb) {
    int r = blockIdx.x, t = threadIdx.x;
    int n, s;
    const float* src;
    if (r < 200) { n = r >> 3; s = r & 7; src = sup; }
    else { int rr = r - 200; n = rr >> 3; s = rr & 7; src = qry; }
    const float4* row = (const float4*)(src + ((size_t)n * SEQ + s) * DM);
    const float4* per = (const float4*)(pe + (size_t)s * DM);
    ushort4* orow = (ushort4*)(pexb + (size_t)r * DM);
    for (int d = t; d < DM / 4; d += 256) {
        float4 a = row[d], p = per[d];
        ushort4 o;
        o.x = f2bits(a.x + p.x); o.y = f2bits(a.y + p.y);
        o.z = f2bits(a.z + p.z); o.w = f2bits(a.w + p.w);
        orow[d] = o;
    }
}

// ---------------------------------------------------------------------------
// Generic MFMA bf16 GEMM: C = scale*A*B^T; z shifts A/B/C by aZ/bZ/cZ elems.
// Proven-fastest schedule: reg stage -> sync -> LDS write -> sync -> ds_read
// -> MFMA, single LDS buffer (compiler gives implicit 1-deep pipeline).
// All explicit rescheduling lost (gload_lds 116/128us, 2-deep 86.5us,
// 1-barrier dbuf 85.2us, LDS-free 180us).
// Templated N-tile; per-call-site choice is MEASUREMENT-BACKED (r6 vs r7):
//   TN=128: projection (K=2048, grid 540)  -> 71.7us; TN=64 there = 84us
//           (bank-conflicts 4.4M->11M, 2x barrier overhead per FLOP).
//   TN=64:  scores/proto (small K, small grids) -> occupancy 19->34% paid
//           (round-7 aggregate -16us on the non-projection pipeline).
// K-accumulation order per output unchanged -> bitwise-identical C.
// XCD-chunked bijective block swizzle kept (FETCH 104->42 MB measured).
// C rows >= mlim are not stored (M-pad garbage containment).
// ---------------------------------------------------------------------------
template <int TN>
__global__ __launch_bounds__(256) void gemm_bt(
    const bf16* __restrict__ A, int lda, size_t aZ,
    const bf16* __restrict__ B, int ldb, size_t bZ,
    float scale, bf16* __restrict__ C, int ldc, size_t cZ, int K, int mlim) {
    constexpr int JN = TN / 32;            // B-frags per wave (2 or 4)
    // ---- XCD swizzle: logical tile id lg from hw block id (bijective) ----
    const int gx = gridDim.x, gy = gridDim.y;
    const int nwg = gx * gy * (int)gridDim.z;
    const int orig = ((int)blockIdx.z * gy + blockIdx.y) * gx + blockIdx.x;
    const int qc = nwg >> 3, rc = nwg & 7;
    const int xcd = orig & 7, sub = orig >> 3;
    const int lg = (xcd < rc ? xcd * (qc + 1) : rc * (qc + 1) + (xcd - rc) * qc) + sub;
    const int bx = lg % gx;
    const int rest = lg / gx;
    const int by = rest % gy, bz = rest / gy;

    const unsigned short* Ag0 = (const unsigned short*)A + aZ * bz;
    const unsigned short* Bg0 = (const unsigned short*)B + bZ * bz;
    const size_t cbase = cZ * bz;
    const int tile_m = bx * 128, tile_n = by * TN;
    __shared__ unsigned short As[4 * 128 * 8];
    __shared__ unsigned short Bs[4 * TN * 8];
    const int t = threadIdx.x, lane = t & 63, wave = t >> 6;
    const int wm = (wave & 1) * 64, wn = (wave >> 1) * (TN / 2);
    const int srow = t >> 1, sq0 = (t & 1) * 2;
    const unsigned short* Ag = Ag0 + (size_t)(tile_m + srow) * lda + (t & 1) * 16;
    unsigned short* AsW0 = &As[((sq0 + 0) * 128 + srow) * 8];
    unsigned short* AsW1 = &As[((sq0 + 1) * 128 + srow) * 8];
    const unsigned short* Bg;
    unsigned short* BsW0;
    unsigned short* BsW1 = nullptr;
    if constexpr (TN == 128) {             // 128 rows x 4 kq: 2 uint4/thread
        Bg = Bg0 + (size_t)(tile_n + srow) * ldb + (t & 1) * 16;
        BsW0 = &Bs[((sq0 + 0) * 128 + srow) * 8];
        BsW1 = &Bs[((sq0 + 1) * 128 + srow) * 8];
    } else {                               // 64 rows x 4 kq: 1 uint4/thread
        Bg = Bg0 + (size_t)(tile_n + (t >> 2)) * ldb + (t & 3) * 8;
        BsW0 = &Bs[((t & 3) * 64 + (t >> 2)) * 8];
    }
    const int fr = lane & 15, quad = lane >> 4;

    f32x4 acc[4][JN];
#pragma unroll
    for (int i = 0; i < 4; i++)
#pragma unroll
        for (int j = 0; j < JN; j++) acc[i][j] = {0.f, 0.f, 0.f, 0.f};

    for (int k0 = 0; k0 < K; k0 += 32) {
        uint4 a0 = *(const uint4*)(Ag + k0);
        uint4 a1 = *(const uint4*)(Ag + k0 + 8);
        uint4 b0 = *(const uint4*)(Bg + k0);
        uint4 b1;
        if constexpr (TN == 128) b1 = *(const uint4*)(Bg + k0 + 8);
        __syncthreads();
        *(uint4*)AsW0 = a0; *(uint4*)AsW1 = a1;
        *(uint4*)BsW0 = b0;
        if constexpr (TN == 128) *(uint4*)BsW1 = b1;
        __syncthreads();
        s16x8 af[4], bfv[JN];
#pragma unroll
        for (int i = 0; i < 4; i++)
            af[i] = *(const s16x8*)&As[(quad * 128 + wm + i * 16 + fr) * 8];
#pragma unroll
        for (int j = 0; j < JN; j++)
            bfv[j] = *(const s16x8*)&Bs[(quad * TN + wn + j * 16 + fr) * 8];
#pragma unroll
        for (int i = 0; i < 4; i++)
#pragma unroll
            for (int j = 0; j < JN; j++)
                acc[i][j] = __builtin_amdgcn_mfma_f32_16x16x32_bf16(af[i], bfv[j], acc[i][j], 0, 0, 0);
    }

    const int rb = quad * 4;
#pragma unroll
    for (int i = 0; i < 4; i++)
#pragma unroll
        for (int j = 0; j < JN; j++) {
            const int col = tile_n + wn + j * 16 + fr;
#pragma unroll
            for (int r = 0; r < 4; r++) {
                const int row = tile_m + wm + i * 16 + rb + r;
                if (row < mlim)
                    C[cbase + (size_t)row * ldc + col] = f2bf(acc[i][j][r] * scale);
            }
        }
}

// ---------------------------------------------------------------------------
// combine_kv (merged, one launch): blocks [0,M_ALL) do the K path (LN),
// blocks [M_ALL, 2*M_ALL) do the V path.  Math identical to the split
// kernels (round-4-verified).
// ---------------------------------------------------------------------------
__global__ __launch_bounds__(256) void combine_kv(
    const unsigned int* __restrict__ Yk, const unsigned int* __restrict__ Yv,
    const float* __restrict__ kb, const float* __restrict__ vb,
    const float* __restrict__ lng, const float* __restrict__ lnb,
    bf16* __restrict__ ks, bf16* __restrict__ vs) {
    const int t = threadIdx.x, lane = t & 63, wave = t >> 6;
    int m = blockIdx.x;
    const bool vpath = m >= M_ALL;
    if (vpath) m -= M_ALL;
    int mm = m < 700 ? m : m - 700;
    int base = m < 700 ? 0 : 200;
    int nsamp = mm / LT, l = mm - nsamp * LT;
    const unsigned int* Y = vpath ? Yv : Yk;
    const unsigned int* ya = Y + (size_t)(base + nsamp * 8 + TUP_A[l]) * (N2 / 2);
    const unsigned int* yb = Y + (size_t)(base + nsamp * 8 + TUP_B[l]) * (N2 / 2);
    if (vpath) {
        for (int n = t; n < OUTD; n += 256) {
            unsigned int ua = ya[n], ub = yb[n];
            vs[(size_t)m * OUTD + n] =
                f2bf(ubits2f(ua & 0xFFFFu) + ubits2f(ub >> 16) + vb[n]);
        }
        return;
    }
    float vals[5];
    int cnt = 0;
    float s = 0.f, s2 = 0.f;
    for (int n = t; n < OUTD; n += 256) {
        unsigned int ua = ya[n], ub = yb[n];
        float vk = ubits2f(ua & 0xFFFFu) + ubits2f(ub >> 16) + kb[n];
        vals[cnt++] = vk;
        s += vk; s2 += vk * vk;
    }
    for (int o = 32; o > 0; o >>= 1) { s += __shfl_xor(s, o); s2 += __shfl_xor(s2, o); }
    __shared__ float r1[4], r2[4];
    if (lane == 0) { r1[wave] = s; r2[wave] = s2; }
    __syncthreads();
    s = r1[0] + r1[1] + r1[2] + r1[3];
    s2 = r2[0] + r2[1] + r2[2] + r2[3];
    float mu = s * (1.f / OUTD);
    float var = s2 * (1.f / OUTD) - mu * mu;
    float inv = rsqrtf(fmaxf(var, 0.f) + 1e-5f);
    cnt = 0;
    for (int n = t; n < OUTD; n += 256)
        ks[(size_t)m * OUTD + n] = f2bf((vals[cnt++] - mu) * inv * lng[n] + lnb[n]);
}

// ---------------------------------------------------------------------------
// sv_k (merged softmax + vspad, one launch, 320 threads):
//  blocks [0,SM): softmax, one WAVE per (row, class), barrier-free
//    (140 = 64+64+12 lane-slots; attn as 5 x 144-col blocks, pad zeroed).
//  blocks [SM, SM+2880): vsp[w][d][j] = vs[w*140+j][d] (j>=140 -> 0);
//    block SM also zeroes gbuf.  2880*320 == 5*OUTD*KP exactly.
// ---------------------------------------------------------------------------
__global__ __launch_bounds__(320) void sv_k(const bf16* __restrict__ sc,
                                            bf16* __restrict__ attn,
                                            const bf16* __restrict__ vs,
                                            bf16* __restrict__ vp,
                                            float* __restrict__ gbuf) {
    const int t = threadIdx.x;
    if (blockIdx.x < SM) {
        const int row = blockIdx.x, w = t >> 6, lane = t & 63;
        const bf16* src = sc + (size_t)row * SN_PAD + w * 140;
        bf16* dst = attn + (size_t)row * ATT_STRIDE + w * ABLK;
        float a = bf2f(src[lane]);
        float b = bf2f(src[lane + 64]);        // lane+64 <= 127 < 140: valid
        float c = (lane < 12) ? bf2f(src[lane + 128]) : -3.0e38f;
        float m = fmaxf(fmaxf(a, b), c);
        for (int o = 32; o > 0; o >>= 1) m = fmaxf(m, __shfl_xor(m, o));
        float ea = __expf(a - m), eb = __expf(b - m);
        float ec = (lane < 12) ? __expf(c - m) : 0.f;
        float s = ea + eb + ec;
        for (int o = 32; o > 0; o >>= 1) s += __shfl_xor(s, o);
        float inv = 1.f / s;
        dst[lane] = f2bf(ea * inv);
        dst[lane + 64] = f2bf(eb * inv);
        if (lane < 16) dst[lane + 128] = f2bf(lane < 12 ? ec * inv : 0.f);
        return;
    }
    const int vb = blockIdx.x - SM;            // 0..2879
    if (vb == 0)
        for (int i = t; i < NQ * 21; i += 320) gbuf[i] = 0.f;
    int idx = vb * 320 + t;                    // < 921600 == 5*OUTD*KP
    int j = idx % KP;
    int rest = idx / KP;
    int dcol = rest % OUTD;
    int w = rest / OUTD;
    vp[idx] = (j < 140) ? vs[(size_t)(w * 140 + j) * OUTD + dcol] : f2bf(0.f);
}

// ---------------------------------------------------------------------------
// Gram reduce over a proto chunk -> 21 sufficient stats per query.
// Vectorized: s16x8 (16B) loads, 2 tuple-rows per block, grid (50,14).
// Rows are 1152 bf16 = 2304 B (16B-aligned), so 16B loads are safe.
// ---------------------------------------------------------------------------
__global__ __launch_bounds__(256) void gramred_k(const bf16* __restrict__ protoc,
                                                 const bf16* __restrict__ vs,
                                                 float* __restrict__ gbuf,
                                                 int row0, int q0) {
    const int ql = blockIdx.x;          // 0..49
    const int lgb = blockIdx.y;         // 0..13 (2 tuple-rows each)
    const int t = threadIdx.x, lane = t & 63, wave = t >> 6;
    const size_t PZ = (size_t)CH_MPAD * OUTD;
    float g[15] = {0.f};
    float h[5] = {0.f, 0.f, 0.f, 0.f, 0.f};
    float e = 0.f;
    for (int idx = t; idx < 2 * OUTD / 8; idx += 256) {   // 288 16B-slots
        int li = idx / 144;
        int dv = idx - li * 144;
        int l = lgb * 2 + li;
        size_t ml = (size_t)(ql * LT + l) * OUTD + dv * 8;
        s16x8 pw0 = *(const s16x8*)&protoc[0 * PZ + ml];
        s16x8 pw1 = *(const s16x8*)&protoc[1 * PZ + ml];
        s16x8 pw2 = *(const s16x8*)&protoc[2 * PZ + ml];
        s16x8 pw3 = *(const s16x8*)&protoc[3 * PZ + ml];
        s16x8 pw4 = *(const s16x8*)&protoc[4 * PZ + ml];
        s16x8 vv = *(const s16x8*)&vs[(size_t)(700 + row0 + ql * LT + l) * OUTD + dv * 8];
#pragma unroll
        for (int ee = 0; ee < 8; ee++) {
            float pv[5];
            pv[0] = ubits2f((unsigned short)pw0[ee]);
            pv[1] = ubits2f((unsigned short)pw1[ee]);
            pv[2] = ubits2f((unsigned short)pw2[ee]);
            pv[3] = ubits2f((unsigned short)pw3[ee]);
            pv[4] = ubits2f((unsigned short)pw4[ee]);
            float v = ubits2f((unsigned short)vv[ee]);
            e += v * v;
            int c = 0;
#pragma unroll
            for (int a = 0; a < 5; a++) {
                h[a] += v * pv[a];
#pragma unroll
                for (int b = a; b < 5; b++) g[c++] += pv[a] * pv[b];
            }
        }
    }
    float vals[21];
#pragma unroll
    for (int k = 0; k < 15; k++) vals[k] = g[k];
#pragma unroll
    for (int k = 0; k < 5; k++) vals[15 + k] = h[k];
    vals[20] = e;
#pragma unroll
    for (int k = 0; k < 21; k++)
        for (int o = 32; o > 0; o >>= 1) vals[k] += __shfl_xor(vals[k], o);
    __shared__ float red[4][21];
    if (lane == 0)
#pragma unroll
        for (int k = 0; k < 21; k++) red[wave][k] = vals[k];
    __syncthreads();
    if (t < 21) {
        float s = red[0][t] + red[1][t] + red[2][t] + red[3][t];
        atomicAdd(&gbuf[(q0 + ql) * 21 + t], s);
    }
}

// ---------------------------------------------------------------------------
// out (fp32): per q -> 25 sim + 5 ori
// ---------------------------------------------------------------------------
__global__ __launch_bounds__(64) void out_k(const float* __restrict__ gbuf,
                                            float* __restrict__ out) {
    int q = blockIdx.x;
    if (threadIdx.x != 0) return;
    const float* r = gbuf + q * 21;
    float G[5][5];
    int c = 0;
    for (int a = 0; a < 5; a++)
        for (int b = a; b < 5; b++) { G[a][b] = r[c]; G[b][a] = r[c]; c++; }
    float e = r[20];
    float nrm[5];
    for (int a = 0; a < 5; a++) nrm[a] = sqrtf(fmaxf(G[a][a], 0.f));
    for (int a = 0; a < 5; a++)
        for (int b = 0; b < 5; b++)
            out[(size_t)q * 25 + a * 5 + b] = G[a][b] / fmaxf(nrm[a] * nrm[b], 1e-8f);
    for (int w = 0; w < 5; w++)
        out[5000 + (size_t)q * 5 + w] = -(e - 2.f * r[15 + w] + G[w][w]) * (1.f / 28.f);
}

// ---------------------------------------------------------------------------
extern "C" void kernel_launch(void* const* d_in, const int* in_sizes, int n_in,
                              void* d_out, int out_size, void* d_ws, size_t ws_size,
                              hipStream_t stream) {
    const float* sup = (const float*)d_in[0];
    // d_in[1] = support_labels int32 — unused (sorted equal-shot)
    const float* qry = (const float*)d_in[2];
    const float* k_w = (const float*)d_in[3];
    const float* k_b = (const float*)d_in[4];
    const float* v_w = (const float*)d_in[5];
    const float* v_b = (const float*)d_in[6];
    const float* lng = (const float*)d_in[7];
    const float* lnb = (const float*)d_in[8];
    (void)in_sizes; (void)n_in; (void)out_size; (void)ws_size;

    // layout (bytes), peak 49,421,728 (<= verified ws_size >= 54.5 MB):
    //   pexb   @0           7,864,320 (1920 rows; 1800 real)  dead after proj
    //   wbf    @7,864,320  18,874,368 (k|v bf16)              dead after proj
    //   Yk     @26,738,688  8,294,400 (1800x2304)             dead after comb_k
    //   Yv     @35,033,088  8,294,400                         dead after comb_v
    //   ks     @0          14,588,928 (6332 rows; 6300 real)  dead after scores
    //   vs     @16,220,160 14,515,200 (6300 rows)             live to end
    //   sc     @30,735,360  8,650,752 (over dead Yk/Yv head)  dead after softmax
    //   vsp    @39,386,112  1,843,200
    //   attn   @41,229,312  8,110,080 (5632 rows x 720; 5 x 144-col blocks)
    //   gbuf   @49,339,392     16,800
    //   pe     @49,356,192     65,536 (8x2048 fp32 table)
    //   protoc @0          16,220,160 (over dead ks, after scores)
    char* ws = (char*)d_ws;
    bf16* pexb   = (bf16*)(ws + 0);
    bf16* wbf    = (bf16*)(ws + 7864320);
    bf16* Yk     = (bf16*)(ws + 26738688);
    bf16* Yv     = (bf16*)(ws + 35033088);
    bf16* ks     = (bf16*)(ws + 0);
    bf16* vs     = (bf16*)(ws + 16220160);
    bf16* sc     = (bf16*)(ws + 30735360);
    bf16* vsp    = (bf16*)(ws + 39386112);
    bf16* attn   = (bf16*)(ws + 41229312);
    float* gbuf  = (float*)(ws + 49339392);
    float* pe    = (float*)(ws + 49356192);
    bf16* protoc = (bf16*)(ws + 0);

    pe_k<<<dim3(64), dim3(256), 0, stream>>>(pe, attn + (size_t)SM * ATT_STRIDE);
    pex_k<<<dim3(1800), dim3(256), 0, stream>>>(sup, qry, pe, pexb);
    wconv2_k<<<dim3(9216), dim3(256), 0, stream>>>(
        (const float4*)k_w, (const float4*)v_w, (ushort4*)wbf);

    // fused K+V projection: z in {k,v}; Y[1800,2304] = pexb @ W_view^T
    // TN=128: measured 71.7us (r6) vs 84us TN=64 (r7) on this call site.
    gemm_bt<128><<<dim3(15, 18, 2), dim3(256), 0, stream>>>(
        pexb, DM, 0, wbf, DM, (size_t)4718592,
        1.0f, Yk, N2, (size_t)4147200, DM, 1800);

    combine_kv<<<dim3(2 * M_ALL), dim3(256), 0, stream>>>(
        (const unsigned int*)Yk, (const unsigned int*)Yv,
        k_b, v_b, lng, lnb, ks, vs);

    // scores: ks_q[5632,1152] @ ks_s[768,1152]^T / sqrt(1152)  (TN=64, r7)
    gemm_bt<64><<<dim3(44, 12, 1), dim3(256), 0, stream>>>(
        ks + (size_t)700 * OUTD, OUTD, 0, ks, OUTD, 0,
        0.029462782549439484f, sc, SN_PAD, 0, OUTD, 5632);

    // merged softmax (5600 blocks) + vspad (2880 blocks), 320 threads
    sv_k<<<dim3(SM + 2880), dim3(320), 0, stream>>>(sc, attn, vs, vsp, gbuf);

    // proto chunks: 4 x 50 queries; per-class GEMM then Gram reduce (TN=64)
    // A = attn with 144-col class blocks (aZ=144, 16B-aligned); K=160 reads
    // spill 16 cols into the next block where vsp's zero columns kill them.
    for (int c = 0; c < 4; c++) {
        gemm_bt<64><<<dim3(11, 18, 5), dim3(256), 0, stream>>>(
            attn + (size_t)c * CH_ROWS * ATT_STRIDE, ATT_STRIDE, (size_t)ABLK,
            vsp, KP, (size_t)OUTD * KP,
            1.0f, protoc, OUTD, (size_t)CH_MPAD * OUTD, KP, CH_MPAD);
        gramred_k<<<dim3(CH_Q, 14), dim3(256), 0, stream>>>(
            protoc, vs, gbuf, c * CH_ROWS, c * CH_Q);
    }

    out_k<<<dim3(NQ), dim3(64), 0, stream>>>(gbuf, (float*)d_out);
}

// Round 10
// 320.368 us; speedup vs baseline: 1.5049x; 1.0202x over previous
//
#include <hip/hip_runtime.h>
#include <hip/hip_bf16.h>
#include <math.h>

typedef __hip_bfloat16 bf16;
typedef short s16x8 __attribute__((ext_vector_type(8)));
typedef float f32x4 __attribute__((ext_vector_type(4)));

#define NQ 200
#define SEQ 8
#define DM 2048
#define OUTD 1152
#define LT 28
#define M_ALL 6300
#define SM 5600
#define SN_PAD 768
#define ATT_STRIDE 720
#define N2 2304          // W viewed as [2304, 2048]
#define KP 160
#define CH_Q 50
#define CH_ROWS 1400
#define CH_MPAD 1408
#define ABLK 144         // attn per-class column block (16B-aligned)

__device__ __forceinline__ float bf2f(bf16 v) { return __bfloat162float(v); }
__device__ __forceinline__ bf16 f2bf(float v) { return __float2bfloat16(v); }
__device__ __forceinline__ float ubits2f(unsigned int u16) {
    unsigned int i = u16 << 16;
    float f; __builtin_memcpy(&f, &i, 4); return f;
}
__device__ __forceinline__ unsigned short f2bits(float f) {
    bf16 b = __float2bfloat16(f);
    unsigned short u; __builtin_memcpy(&u, &b, 2); return u;
}

__device__ const int TUP_A[LT] = {0,0,0,0,0,0,0,1,1,1,1,1,1,2,2,2,2,2,3,3,3,3,4,4,4,5,5,6};
__device__ const int TUP_B[LT] = {1,2,3,4,5,6,7,2,3,4,5,6,7,3,4,5,6,7,4,5,6,7,5,6,7,6,7,7};

// ---------------------------------------------------------------------------
// fused weight convert: [k_w | v_w] fp32 -> bf16 (2 x 1,179,648 float4)
// ---------------------------------------------------------------------------
__global__ __launch_bounds__(256) void wconv2_k(const float4* __restrict__ kw,
                                                const float4* __restrict__ vw,
                                                ushort4* __restrict__ o) {
    int i = blockIdx.x * 256 + threadIdx.x;     // 0 .. 2,359,295
    float4 v = (i < 1179648) ? kw[i] : vw[i - 1179648];
    ushort4 r;
    r.x = f2bits(v.x); r.y = f2bits(v.y); r.z = f2bits(v.z); r.w = f2bits(v.w);
    o[i] = r;
}

// ---------------------------------------------------------------------------
// pe table: pe[s][d], 8 x 2048 fp32 (trig computed once, not 1800x).
// Also zeroes attn tail rows 5600..5631 (never written by softmax; the proto
// GEMM's K-spill reads next-row cols 0..15, so uninit bf16 there could be
// NaN and NaN*0 would poison protoc row 1399).
// ---------------------------------------------------------------------------
__global__ __launch_bounds__(256) void pe_k(float* __restrict__ pe,
                                            bf16* __restrict__ attn_tail) {
    int i = blockIdx.x * 256 + threadIdx.x;     // 0 .. 16383
    int s = i >> 11, d = i & 2047;
    float dv = expf((float)(d & ~1) * (-9.210340371976184f / 2048.0f));
    float ang = (float)s * dv;
    pe[i] = (d & 1) ? cosf(ang) * 0.1f : sinf(ang) * 0.1f;
    for (int j = i; j < 32 * ATT_STRIDE; j += 64 * 256) attn_tail[j] = f2bf(0.f);
}

// ---------------------------------------------------------------------------
// pexb[r][d] = fp32 src[n][s][d] + pe[s][d] -> bf16 (1800 rows, vectorized)
// ---------------------------------------------------------------------------
__global__ __launch_bounds__(256) void pex_k(const float* __restrict__ sup,
                                             const float* __restrict__ qry,
                                             const float* __restrict__ pe,
                                             bf16* __restrict__ pexb) {
    int r = blockIdx.x, t = threadIdx.x;
    int n, s;
    const float* src;
    if (r < 200) { n = r >> 3; s = r & 7; src = sup; }
    else { int rr = r - 200; n = rr >> 3; s = rr & 7; src = qry; }
    const float4* row = (const float4*)(src + ((size_t)n * SEQ + s) * DM);
    const float4* per = (const float4*)(pe + (size_t)s * DM);
    ushort4* orow = (ushort4*)(pexb + (size_t)r * DM);
    for (int d = t; d < DM / 4; d += 256) {
        float4 a = row[d], p = per[d];
        ushort4 o;
        o.x = f2bits(a.x + p.x); o.y = f2bits(a.y + p.y);
        o.z = f2bits(a.z + p.z); o.w = f2bits(a.w + p.w);
        orow[d] = o;
    }
}

// ---------------------------------------------------------------------------
// Generic MFMA bf16 GEMM: C = scale*A*B^T; z shifts A/B/C by aZ/bZ/cZ elems.
// Proven-fastest schedule: reg stage -> sync -> LDS write -> sync -> ds_read
// -> MFMA, single LDS buffer (compiler gives implicit 1-deep pipeline).
// All explicit rescheduling lost (gload_lds 116/128us, 2-deep 86.5us,
// 1-barrier dbuf 85.2us, LDS-free 180us).
// Templated N-tile; per-call-site choice is MEASUREMENT-BACKED (r6/r7/r8):
//   TN=128: projection (K=2048, grid 540)  -> 71.7us; TN=64 there = 84us.
//   TN=64:  scores/proto (small K, small grids) -> occupancy 19->34% paid.
// K-accumulation order per output unchanged -> bitwise-identical C.
// XCD-chunked bijective block swizzle kept (FETCH 104->42 MB measured).
// C rows >= mlim are not stored (M-pad garbage containment).
// ---------------------------------------------------------------------------
template <int TN>
__global__ __launch_bounds__(256) void gemm_bt(
    const bf16* __restrict__ A, int lda, size_t aZ,
    const bf16* __restrict__ B, int ldb, size_t bZ,
    float scale, bf16* __restrict__ C, int ldc, size_t cZ, int K, int mlim) {
    constexpr int JN = TN / 32;            // B-frags per wave (2 or 4)
    // ---- XCD swizzle: logical tile id lg from hw block id (bijective) ----
    const int gx = gridDim.x, gy = gridDim.y;
    const int nwg = gx * gy * (int)gridDim.z;
    const int orig = ((int)blockIdx.z * gy + blockIdx.y) * gx + blockIdx.x;
    const int qc = nwg >> 3, rc = nwg & 7;
    const int xcd = orig & 7, sub = orig >> 3;
    const int lg = (xcd < rc ? xcd * (qc + 1) : rc * (qc + 1) + (xcd - rc) * qc) + sub;
    const int bx = lg % gx;
    const int rest = lg / gx;
    const int by = rest % gy, bz = rest / gy;

    const unsigned short* Ag0 = (const unsigned short*)A + aZ * bz;
    const unsigned short* Bg0 = (const unsigned short*)B + bZ * bz;
    const size_t cbase = cZ * bz;
    const int tile_m = bx * 128, tile_n = by * TN;
    __shared__ unsigned short As[4 * 128 * 8];
    __shared__ unsigned short Bs[4 * TN * 8];
    const int t = threadIdx.x, lane = t & 63, wave = t >> 6;
    const int wm = (wave & 1) * 64, wn = (wave >> 1) * (TN / 2);
    const int srow = t >> 1, sq0 = (t & 1) * 2;
    const unsigned short* Ag = Ag0 + (size_t)(tile_m + srow) * lda + (t & 1) * 16;
    unsigned short* AsW0 = &As[((sq0 + 0) * 128 + srow) * 8];
    unsigned short* AsW1 = &As[((sq0 + 1) * 128 + srow) * 8];
    const unsigned short* Bg;
    unsigned short* BsW0;
    unsigned short* BsW1 = nullptr;
    if constexpr (TN == 128) {             // 128 rows x 4 kq: 2 uint4/thread
        Bg = Bg0 + (size_t)(tile_n + srow) * ldb + (t & 1) * 16;
        BsW0 = &Bs[((sq0 + 0) * 128 + srow) * 8];
        BsW1 = &Bs[((sq0 + 1) * 128 + srow) * 8];
    } else {                               // 64 rows x 4 kq: 1 uint4/thread
        Bg = Bg0 + (size_t)(tile_n + (t >> 2)) * ldb + (t & 3) * 8;
        BsW0 = &Bs[((t & 3) * 64 + (t >> 2)) * 8];
    }
    const int fr = lane & 15, quad = lane >> 4;

    f32x4 acc[4][JN];
#pragma unroll
    for (int i = 0; i < 4; i++)
#pragma unroll
        for (int j = 0; j < JN; j++) acc[i][j] = {0.f, 0.f, 0.f, 0.f};

    for (int k0 = 0; k0 < K; k0 += 32) {
        uint4 a0 = *(const uint4*)(Ag + k0);
        uint4 a1 = *(const uint4*)(Ag + k0 + 8);
        uint4 b0 = *(const uint4*)(Bg + k0);
        uint4 b1;
        if constexpr (TN == 128) b1 = *(const uint4*)(Bg + k0 + 8);
        __syncthreads();
        *(uint4*)AsW0 = a0; *(uint4*)AsW1 = a1;
        *(uint4*)BsW0 = b0;
        if constexpr (TN == 128) *(uint4*)BsW1 = b1;
        __syncthreads();
        s16x8 af[4], bfv[JN];
#pragma unroll
        for (int i = 0; i < 4; i++)
            af[i] = *(const s16x8*)&As[(quad * 128 + wm + i * 16 + fr) * 8];
#pragma unroll
        for (int j = 0; j < JN; j++)
            bfv[j] = *(const s16x8*)&Bs[(quad * TN + wn + j * 16 + fr) * 8];
#pragma unroll
        for (int i = 0; i < 4; i++)
#pragma unroll
            for (int j = 0; j < JN; j++)
                acc[i][j] = __builtin_amdgcn_mfma_f32_16x16x32_bf16(af[i], bfv[j], acc[i][j], 0, 0, 0);
    }

    const int rb = quad * 4;
#pragma unroll
    for (int i = 0; i < 4; i++)
#pragma unroll
        for (int j = 0; j < JN; j++) {
            const int col = tile_n + wn + j * 16 + fr;
#pragma unroll
            for (int r = 0; r < 4; r++) {
                const int row = tile_m + wm + i * 16 + rb + r;
                if (row < mlim)
                    C[cbase + (size_t)row * ldc + col] = f2bf(acc[i][j][r] * scale);
            }
        }
}

// ---------------------------------------------------------------------------
// combine_kv (merged, one launch): blocks [0,M_ALL) -> K path (LN),
// blocks [M_ALL, 2*M_ALL) -> V path.
// NEW (r9): (a) G13-vectorized: uint4 Y-row loads (16B/lane), float4 params,
// ushort4 stores (rows are 4608B = 288x16B; ks/vs rows 2304B -> 8B-aligned
// stores at 4-elem steps).  (b) XCD-chunked bijective swizzle WITHIN each
// path (nwg=6300, rc=4): a sample's 28 tuples land on one XCD so its 8
// shared Y-rows are L2-resident there (were L3-served round-robin).  Per-path
// swizzle keeps LN-heavy K blocks balanced across all XCDs.
// ---------------------------------------------------------------------------
__global__ __launch_bounds__(256) void combine_kv(
    const unsigned int* __restrict__ Yk, const unsigned int* __restrict__ Yv,
    const float* __restrict__ kb, const float* __restrict__ vb,
    const float* __restrict__ lng, const float* __restrict__ lnb,
    bf16* __restrict__ ks, bf16* __restrict__ vs) {
    const int t = threadIdx.x, lane = t & 63, wave = t >> 6;
    int orig = blockIdx.x;
    const bool vpath = orig >= M_ALL;
    if (vpath) orig -= M_ALL;
    // bijective chunked swizzle over 6300 (qc=787, rc=4)
    {
        const int qc = M_ALL >> 3, rc = M_ALL & 7;
        const int xcd = orig & 7, sub = orig >> 3;
        orig = (xcd < rc ? xcd * (qc + 1) : rc * (qc + 1) + (xcd - rc) * qc) + sub;
    }
    const int m = orig;
    int mm = m < 700 ? m : m - 700;
    int base = m < 700 ? 0 : 200;
    int nsamp = mm / LT, l = mm - nsamp * LT;
    const unsigned int* Y = vpath ? Yv : Yk;
    const uint4* ya4 = (const uint4*)(Y + (size_t)(base + nsamp * 8 + TUP_A[l]) * (N2 / 2));
    const uint4* yb4 = (const uint4*)(Y + (size_t)(base + nsamp * 8 + TUP_B[l]) * (N2 / 2));
    if (vpath) {
        const float4* vb4 = (const float4*)vb;
        for (int u = t; u < OUTD / 4; u += 256) {       // 288 slots
            uint4 a4 = ya4[u], b4 = yb4[u];
            float4 c4 = vb4[u];
            ushort4 o;
            o.x = f2bits(ubits2f(a4.x & 0xFFFFu) + ubits2f(b4.x >> 16) + c4.x);
            o.y = f2bits(ubits2f(a4.y & 0xFFFFu) + ubits2f(b4.y >> 16) + c4.y);
            o.z = f2bits(ubits2f(a4.z & 0xFFFFu) + ubits2f(b4.z >> 16) + c4.z);
            o.w = f2bits(ubits2f(a4.w & 0xFFFFu) + ubits2f(b4.w >> 16) + c4.w);
            *(ushort4*)&vs[(size_t)m * OUTD + u * 4] = o;
        }
        return;
    }
    const float4* kb4 = (const float4*)kb;
    float vals[8];                                      // <= 2 iters x 4
    int cnt = 0;
    float s = 0.f, s2 = 0.f;
    for (int u = t; u < OUTD / 4; u += 256) {
        uint4 a4 = ya4[u], b4 = yb4[u];
        float4 c4 = kb4[u];
        float v0 = ubits2f(a4.x & 0xFFFFu) + ubits2f(b4.x >> 16) + c4.x;
        float v1 = ubits2f(a4.y & 0xFFFFu) + ubits2f(b4.y >> 16) + c4.y;
        float v2 = ubits2f(a4.z & 0xFFFFu) + ubits2f(b4.z >> 16) + c4.z;
        float v3 = ubits2f(a4.w & 0xFFFFu) + ubits2f(b4.w >> 16) + c4.w;
        vals[cnt] = v0; vals[cnt + 1] = v1; vals[cnt + 2] = v2; vals[cnt + 3] = v3;
        cnt += 4;
        s += (v0 + v1) + (v2 + v3);
        s2 += v0 * v0 + v1 * v1 + v2 * v2 + v3 * v3;
    }
    for (int o = 32; o > 0; o >>= 1) { s += __shfl_xor(s, o); s2 += __shfl_xor(s2, o); }
    __shared__ float r1[4], r2[4];
    if (lane == 0) { r1[wave] = s; r2[wave] = s2; }
    __syncthreads();
    s = r1[0] + r1[1] + r1[2] + r1[3];
    s2 = r2[0] + r2[1] + r2[2] + r2[3];
    float mu = s * (1.f / OUTD);
    float var = s2 * (1.f / OUTD) - mu * mu;
    float inv = rsqrtf(fmaxf(var, 0.f) + 1e-5f);
    const float4* lg4 = (const float4*)lng;
    const float4* lb4 = (const float4*)lnb;
    cnt = 0;
    for (int u = t; u < OUTD / 4; u += 256) {
        float4 g4 = lg4[u], b4v = lb4[u];
        ushort4 o;
        o.x = f2bits((vals[cnt]     - mu) * inv * g4.x + b4v.x);
        o.y = f2bits((vals[cnt + 1] - mu) * inv * g4.y + b4v.y);
        o.z = f2bits((vals[cnt + 2] - mu) * inv * g4.z + b4v.z);
        o.w = f2bits((vals[cnt + 3] - mu) * inv * g4.w + b4v.w);
        cnt += 4;
        *(ushort4*)&ks[(size_t)m * OUTD + u * 4] = o;
    }
}

// ---------------------------------------------------------------------------
// sv_k (merged softmax + vspad, one launch, 320 threads):
//  blocks [0,SM): softmax, one WAVE per (row, class), barrier-free
//    (140 = 64+64+12 lane-slots; attn as 5 x 144-col blocks, pad zeroed).
//  blocks [SM, SM+2880): vsp[w][d][j] = vs[w*140+j][d] (j>=140 -> 0);
//    block SM also zeroes gbuf.  2880*320 == 5*OUTD*KP exactly.
// ---------------------------------------------------------------------------
__global__ __launch_bounds__(320) void sv_k(const bf16* __restrict__ sc,
                                            bf16* __restrict__ attn,
                                            const bf16* __restrict__ vs,
                                            bf16* __restrict__ vp,
                                            float* __restrict__ gbuf) {
    const int t = threadIdx.x;
    if (blockIdx.x < SM) {
        const int row = blockIdx.x, w = t >> 6, lane = t & 63;
        const bf16* src = sc + (size_t)row * SN_PAD + w * 140;
        bf16* dst = attn + (size_t)row * ATT_STRIDE + w * ABLK;
        float a = bf2f(src[lane]);
        float b = bf2f(src[lane + 64]);        // lane+64 <= 127 < 140: valid
        float c = (lane < 12) ? bf2f(src[lane + 128]) : -3.0e38f;
        float m = fmaxf(fmaxf(a, b), c);
        for (int o = 32; o > 0; o >>= 1) m = fmaxf(m, __shfl_xor(m, o));
        float ea = __expf(a - m), eb = __expf(b - m);
        float ec = (lane < 12) ? __expf(c - m) : 0.f;
        float s = ea + eb + ec;
        for (int o = 32; o > 0; o >>= 1) s += __shfl_xor(s, o);
        float inv = 1.f / s;
        dst[lane] = f2bf(ea * inv);
        dst[lane + 64] = f2bf(eb * inv);
        if (lane < 16) dst[lane + 128] = f2bf(lane < 12 ? ec * inv : 0.f);
        return;
    }
    const int vb = blockIdx.x - SM;            // 0..2879
    if (vb == 0)
        for (int i = t; i < NQ * 21; i += 320) gbuf[i] = 0.f;
    int idx = vb * 320 + t;                    // < 921600 == 5*OUTD*KP
    int j = idx % KP;
    int rest = idx / KP;
    int dcol = rest % OUTD;
    int w = rest / OUTD;
    vp[idx] = (j < 140) ? vs[(size_t)(w * 140 + j) * OUTD + dcol] : f2bf(0.f);
}

// ---------------------------------------------------------------------------
// Gram reduce over a proto chunk -> 21 sufficient stats per query.
// Vectorized: s16x8 (16B) loads, 2 tuple-rows per block, grid (50,14).
// Rows are 1152 bf16 = 2304 B (16B-aligned), so 16B loads are safe.
// ---------------------------------------------------------------------------
__global__ __launch_bounds__(256) void gramred_k(const bf16* __restrict__ protoc,
                                                 const bf16* __restrict__ vs,
                                                 float* __restrict__ gbuf,
                                                 int row0, int q0) {
    const int ql = blockIdx.x;          // 0..49
    const int lgb = blockIdx.y;         // 0..13 (2 tuple-rows each)
    const int t = threadIdx.x, lane = t & 63, wave = t >> 6;
    const size_t PZ = (size_t)CH_MPAD * OUTD;
    float g[15] = {0.f};
    float h[5] = {0.f, 0.f, 0.f, 0.f, 0.f};
    float e = 0.f;
    for (int idx = t; idx < 2 * OUTD / 8; idx += 256) {   // 288 16B-slots
        int li = idx / 144;
        int dv = idx - li * 144;
        int l = lgb * 2 + li;
        size_t ml = (size_t)(ql * LT + l) * OUTD + dv * 8;
        s16x8 pw0 = *(const s16x8*)&protoc[0 * PZ + ml];
        s16x8 pw1 = *(const s16x8*)&protoc[1 * PZ + ml];
        s16x8 pw2 = *(const s16x8*)&protoc[2 * PZ + ml];
        s16x8 pw3 = *(const s16x8*)&protoc[3 * PZ + ml];
        s16x8 pw4 = *(const s16x8*)&protoc[4 * PZ + ml];
        s16x8 vv = *(const s16x8*)&vs[(size_t)(700 + row0 + ql * LT + l) * OUTD + dv * 8];
#pragma unroll
        for (int ee = 0; ee < 8; ee++) {
            float pv[5];
            pv[0] = ubits2f((unsigned short)pw0[ee]);
            pv[1] = ubits2f((unsigned short)pw1[ee]);
            pv[2] = ubits2f((unsigned short)pw2[ee]);
            pv[3] = ubits2f((unsigned short)pw3[ee]);
            pv[4] = ubits2f((unsigned short)pw4[ee]);
            float v = ubits2f((unsigned short)vv[ee]);
            e += v * v;
            int c = 0;
#pragma unroll
            for (int a = 0; a < 5; a++) {
                h[a] += v * pv[a];
#pragma unroll
                for (int b = a; b < 5; b++) g[c++] += pv[a] * pv[b];
            }
        }
    }
    float vals[21];
#pragma unroll
    for (int k = 0; k < 15; k++) vals[k] = g[k];
#pragma unroll
    for (int k = 0; k < 5; k++) vals[15 + k] = h[k];
    vals[20] = e;
#pragma unroll
    for (int k = 0; k < 21; k++)
        for (int o = 32; o > 0; o >>= 1) vals[k] += __shfl_xor(vals[k], o);
    __shared__ float red[4][21];
    if (lane == 0)
#pragma unroll
        for (int k = 0; k < 21; k++) red[wave][k] = vals[k];
    __syncthreads();
    if (t < 21) {
        float s = red[0][t] + red[1][t] + red[2][t] + red[3][t];
        atomicAdd(&gbuf[(q0 + ql) * 21 + t], s);
    }
}

// ---------------------------------------------------------------------------
// out (fp32): per q -> 25 sim + 5 ori
// ---------------------------------------------------------------------------
__global__ __launch_bounds__(64) void out_k(const float* __restrict__ gbuf,
                                            float* __restrict__ out) {
    int q = blockIdx.x;
    if (threadIdx.x != 0) return;
    const float* r = gbuf + q * 21;
    float G[5][5];
    int c = 0;
    for (int a = 0; a < 5; a++)
        for (int b = a; b < 5; b++) { G[a][b] = r[c]; G[b][a] = r[c]; c++; }
    float e = r[20];
    float nrm[5];
    for (int a = 0; a < 5; a++) nrm[a] = sqrtf(fmaxf(G[a][a], 0.f));
    for (int a = 0; a < 5; a++)
        for (int b = 0; b < 5; b++)
            out[(size_t)q * 25 + a * 5 + b] = G[a][b] / fmaxf(nrm[a] * nrm[b], 1e-8f);
    for (int w = 0; w < 5; w++)
        out[5000 + (size_t)q * 5 + w] = -(e - 2.f * r[15 + w] + G[w][w]) * (1.f / 28.f);
}

// ---------------------------------------------------------------------------
extern "C" void kernel_launch(void* const* d_in, const int* in_sizes, int n_in,
                              void* d_out, int out_size, void* d_ws, size_t ws_size,
                              hipStream_t stream) {
    const float* sup = (const float*)d_in[0];
    // d_in[1] = support_labels int32 — unused (sorted equal-shot)
    const float* qry = (const float*)d_in[2];
    const float* k_w = (const float*)d_in[3];
    const float* k_b = (const float*)d_in[4];
    const float* v_w = (const float*)d_in[5];
    const float* v_b = (const float*)d_in[6];
    const float* lng = (const float*)d_in[7];
    const float* lnb = (const float*)d_in[8];
    (void)in_sizes; (void)n_in; (void)out_size; (void)ws_size;

    // layout (bytes), peak 49,421,728 (<= verified ws_size >= 54.5 MB):
    //   pexb   @0           7,864,320 (1920 rows; 1800 real)  dead after proj
    //   wbf    @7,864,320  18,874,368 (k|v bf16)              dead after proj
    //   Yk     @26,738,688  8,294,400 (1800x2304)             dead after comb_k
    //   Yv     @35,033,088  8,294,400                         dead after comb_v
    //   ks     @0          14,588,928 (6332 rows; 6300 real)  dead after scores
    //   vs     @16,220,160 14,515,200 (6300 rows)             live to end
    //   sc     @30,735,360  8,650,752 (over dead Yk/Yv head)  dead after softmax
    //   vsp    @39,386,112  1,843,200
    //   attn   @41,229,312  8,110,080 (5632 rows x 720; 5 x 144-col blocks)
    //   gbuf   @49,339,392     16,800
    //   pe     @49,356,192     65,536 (8x2048 fp32 table)
    //   protoc @0          16,220,160 (over dead ks, after scores)
    char* ws = (char*)d_ws;
    bf16* pexb   = (bf16*)(ws + 0);
    bf16* wbf    = (bf16*)(ws + 7864320);
    bf16* Yk     = (bf16*)(ws + 26738688);
    bf16* Yv     = (bf16*)(ws + 35033088);
    bf16* ks     = (bf16*)(ws + 0);
    bf16* vs     = (bf16*)(ws + 16220160);
    bf16* sc     = (bf16*)(ws + 30735360);
    bf16* vsp    = (bf16*)(ws + 39386112);
    bf16* attn   = (bf16*)(ws + 41229312);
    float* gbuf  = (float*)(ws + 49339392);
    float* pe    = (float*)(ws + 49356192);
    bf16* protoc = (bf16*)(ws + 0);

    pe_k<<<dim3(64), dim3(256), 0, stream>>>(pe, attn + (size_t)SM * ATT_STRIDE);
    pex_k<<<dim3(1800), dim3(256), 0, stream>>>(sup, qry, pe, pexb);
    wconv2_k<<<dim3(9216), dim3(256), 0, stream>>>(
        (const float4*)k_w, (const float4*)v_w, (ushort4*)wbf);

    // fused K+V projection: z in {k,v}; Y[1800,2304] = pexb @ W_view^T
    // TN=128: measured 71.7us (r6/r8) vs 84us TN=64 (r7) on this call site.
    gemm_bt<128><<<dim3(15, 18, 2), dim3(256), 0, stream>>>(
        pexb, DM, 0, wbf, DM, (size_t)4718592,
        1.0f, Yk, N2, (size_t)4147200, DM, 1800);

    combine_kv<<<dim3(2 * M_ALL), dim3(256), 0, stream>>>(
        (const unsigned int*)Yk, (const unsigned int*)Yv,
        k_b, v_b, lng, lnb, ks, vs);

    // scores: ks_q[5632,1152] @ ks_s[768,1152]^T / sqrt(1152)  (TN=64, r7)
    gemm_bt<64><<<dim3(44, 12, 1), dim3(256), 0, stream>>>(
        ks + (size_t)700 * OUTD, OUTD, 0, ks, OUTD, 0,
        0.029462782549439484f, sc, SN_PAD, 0, OUTD, 5632);

    // merged softmax (5600 blocks) + vspad (2880 blocks), 320 threads
    sv_k<<<dim3(SM + 2880), dim3(320), 0, stream>>>(sc, attn, vs, vsp, gbuf);

    // proto chunks: 4 x 50 queries; per-class GEMM then Gram reduce (TN=64)
    // A = attn with 144-col class blocks (aZ=144, 16B-aligned); K=160 reads
    // spill 16 cols into the next block where vsp's zero columns kill them.
    for (int c = 0; c < 4; c++) {
        gemm_bt<64><<<dim3(11, 18, 5), dim3(256), 0, stream>>>(
            attn + (size_t)c * CH_ROWS * ATT_STRIDE, ATT_STRIDE, (size_t)ABLK,
            vsp, KP, (size_t)OUTD * KP,
            1.0f, protoc, OUTD, (size_t)CH_MPAD * OUTD, KP, CH_MPAD);
        gramred_k<<<dim3(CH_Q, 14), dim3(256), 0, stream>>>(
            protoc, vs, gbuf, c * CH_ROWS, c * CH_Q);
    }

    out_k<<<dim3(NQ), dim3(64), 0, stream>>>(gbuf, (float*)d_out);
}

// Round 11
// 293.668 us; speedup vs baseline: 1.6417x; 1.0909x over previous
//
#include <hip/hip_runtime.h>
#include <hip/hip_bf16.h>
#include <math.h>

typedef __hip_bfloat16 bf16;
typedef short s16x8 __attribute__((ext_vector_type(8)));
typedef float f32x4 __attribute__((ext_vector_type(4)));

#define NQ 200
#define SEQ 8
#define DM 2048
#define OUTD 1152
#define LT 28
#define M_ALL 6300
#define SM 5600
#define SN_PAD 768
#define ATT_STRIDE 720
#define N2 2304          // W viewed as [2304, 2048]
#define KP 160
#define ABLK 144         // attn per-class column block (16B-aligned)

__device__ __forceinline__ float bf2f(bf16 v) { return __bfloat162float(v); }
__device__ __forceinline__ bf16 f2bf(float v) { return __float2bfloat16(v); }
__device__ __forceinline__ float ubits2f(unsigned int u16) {
    unsigned int i = u16 << 16;
    float f; __builtin_memcpy(&f, &i, 4); return f;
}
__device__ __forceinline__ unsigned short f2bits(float f) {
    bf16 b = __float2bfloat16(f);
    unsigned short u; __builtin_memcpy(&u, &b, 2); return u;
}

__device__ const int TUP_A[LT] = {0,0,0,0,0,0,0,1,1,1,1,1,1,2,2,2,2,2,3,3,3,3,4,4,4,5,5,6};
__device__ const int TUP_B[LT] = {1,2,3,4,5,6,7,2,3,4,5,6,7,3,4,5,6,7,4,5,6,7,5,6,7,6,7,7};

// ---------------------------------------------------------------------------
// fused weight convert: [k_w | v_w] fp32 -> bf16 (2 x 1,179,648 float4)
// ---------------------------------------------------------------------------
__global__ __launch_bounds__(256) void wconv2_k(const float4* __restrict__ kw,
                                                const float4* __restrict__ vw,
                                                ushort4* __restrict__ o) {
    int i = blockIdx.x * 256 + threadIdx.x;     // 0 .. 2,359,295
    float4 v = (i < 1179648) ? kw[i] : vw[i - 1179648];
    ushort4 r;
    r.x = f2bits(v.x); r.y = f2bits(v.y); r.z = f2bits(v.z); r.w = f2bits(v.w);
    o[i] = r;
}

// ---------------------------------------------------------------------------
// pe table: pe[s][d], 8 x 2048 fp32 (trig computed once, not 1800x).
// Also zeroes attn tail rows 5600..5631 (never written by softmax; fproto's
// q=199 block reads rows up to 5604 incl. k-spill -> must be finite/zero).
// ---------------------------------------------------------------------------
__global__ __launch_bounds__(256) void pe_k(float* __restrict__ pe,
                                            bf16* __restrict__ attn_tail) {
    int i = blockIdx.x * 256 + threadIdx.x;     // 0 .. 16383
    int s = i >> 11, d = i & 2047;
    float dv = expf((float)(d & ~1) * (-9.210340371976184f / 2048.0f));
    float ang = (float)s * dv;
    pe[i] = (d & 1) ? cosf(ang) * 0.1f : sinf(ang) * 0.1f;
    for (int j = i; j < 32 * ATT_STRIDE; j += 64 * 256) attn_tail[j] = f2bf(0.f);
}

// ---------------------------------------------------------------------------
// pexb[r][d] = fp32 src[n][s][d] + pe[s][d] -> bf16 (1800 rows, vectorized)
// ---------------------------------------------------------------------------
__global__ __launch_bounds__(256) void pex_k(const float* __restrict__ sup,
                                             const float* __restrict__ qry,
                                             const float* __restrict__ pe,
                                             bf16* __restrict__ pexb) {
    int r = blockIdx.x, t = threadIdx.x;
    int n, s;
    const float* src;
    if (r < 200) { n = r >> 3; s = r & 7; src = sup; }
    else { int rr = r - 200; n = rr >> 3; s = rr & 7; src = qry; }
    const float4* row = (const float4*)(src + ((size_t)n * SEQ + s) * DM);
    const float4* per = (const float4*)(pe + (size_t)s * DM);
    ushort4* orow = (ushort4*)(pexb + (size_t)r * DM);
    for (int d = t; d < DM / 4; d += 256) {
        float4 a = row[d], p = per[d];
        ushort4 o;
        o.x = f2bits(a.x + p.x); o.y = f2bits(a.y + p.y);
        o.z = f2bits(a.z + p.z); o.w = f2bits(a.w + p.w);
        orow[d] = o;
    }
}

// ---------------------------------------------------------------------------
// Generic MFMA bf16 GEMM: C = scale*A*B^T; z shifts A/B/C by aZ/bZ/cZ elems.
// Proven-fastest schedule: reg stage -> sync -> LDS write -> sync -> ds_read
// -> MFMA, single LDS buffer (compiler gives implicit 1-deep pipeline).
// Templated N-tile; per-call-site choice is MEASUREMENT-BACKED (r6/r7/r8):
//   TN=128: projection (K=2048, grid 540)  -> 71.7us; TN=64 there = 84us.
//   TN=64:  scores (small K, small grid) -> occupancy 19->34% paid.
// XCD-chunked bijective block swizzle kept (FETCH 104->42 MB measured).
// C rows >= mlim are not stored (M-pad garbage containment).
// ---------------------------------------------------------------------------
template <int TN>
__global__ __launch_bounds__(256) void gemm_bt(
    const bf16* __restrict__ A, int lda, size_t aZ,
    const bf16* __restrict__ B, int ldb, size_t bZ,
    float scale, bf16* __restrict__ C, int ldc, size_t cZ, int K, int mlim) {
    constexpr int JN = TN / 32;            // B-frags per wave (2 or 4)
    // ---- XCD swizzle: logical tile id lg from hw block id (bijective) ----
    const int gx = gridDim.x, gy = gridDim.y;
    const int nwg = gx * gy * (int)gridDim.z;
    const int orig = ((int)blockIdx.z * gy + blockIdx.y) * gx + blockIdx.x;
    const int qc = nwg >> 3, rc = nwg & 7;
    const int xcd = orig & 7, sub = orig >> 3;
    const int lg = (xcd < rc ? xcd * (qc + 1) : rc * (qc + 1) + (xcd - rc) * qc) + sub;
    const int bx = lg % gx;
    const int rest = lg / gx;
    const int by = rest % gy, bz = rest / gy;

    const unsigned short* Ag0 = (const unsigned short*)A + aZ * bz;
    const unsigned short* Bg0 = (const unsigned short*)B + bZ * bz;
    const size_t cbase = cZ * bz;
    const int tile_m = bx * 128, tile_n = by * TN;
    __shared__ unsigned short As[4 * 128 * 8];
    __shared__ unsigned short Bs[4 * TN * 8];
    const int t = threadIdx.x, lane = t & 63, wave = t >> 6;
    const int wm = (wave & 1) * 64, wn = (wave >> 1) * (TN / 2);
    const int srow = t >> 1, sq0 = (t & 1) * 2;
    const unsigned short* Ag = Ag0 + (size_t)(tile_m + srow) * lda + (t & 1) * 16;
    unsigned short* AsW0 = &As[((sq0 + 0) * 128 + srow) * 8];
    unsigned short* AsW1 = &As[((sq0 + 1) * 128 + srow) * 8];
    const unsigned short* Bg;
    unsigned short* BsW0;
    unsigned short* BsW1 = nullptr;
    if constexpr (TN == 128) {             // 128 rows x 4 kq: 2 uint4/thread
        Bg = Bg0 + (size_t)(tile_n + srow) * ldb + (t & 1) * 16;
        BsW0 = &Bs[((sq0 + 0) * 128 + srow) * 8];
        BsW1 = &Bs[((sq0 + 1) * 128 + srow) * 8];
    } else {                               // 64 rows x 4 kq: 1 uint4/thread
        Bg = Bg0 + (size_t)(tile_n + (t >> 2)) * ldb + (t & 3) * 8;
        BsW0 = &Bs[((t & 3) * 64 + (t >> 2)) * 8];
    }
    const int fr = lane & 15, quad = lane >> 4;

    f32x4 acc[4][JN];
#pragma unroll
    for (int i = 0; i < 4; i++)
#pragma unroll
        for (int j = 0; j < JN; j++) acc[i][j] = {0.f, 0.f, 0.f, 0.f};

    for (int k0 = 0; k0 < K; k0 += 32) {
        uint4 a0 = *(const uint4*)(Ag + k0);
        uint4 a1 = *(const uint4*)(Ag + k0 + 8);
        uint4 b0 = *(const uint4*)(Bg + k0);
        uint4 b1;
        if constexpr (TN == 128) b1 = *(const uint4*)(Bg + k0 + 8);
        __syncthreads();
        *(uint4*)AsW0 = a0; *(uint4*)AsW1 = a1;
        *(uint4*)BsW0 = b0;
        if constexpr (TN == 128) *(uint4*)BsW1 = b1;
        __syncthreads();
        s16x8 af[4], bfv[JN];
#pragma unroll
        for (int i = 0; i < 4; i++)
            af[i] = *(const s16x8*)&As[(quad * 128 + wm + i * 16 + fr) * 8];
#pragma unroll
        for (int j = 0; j < JN; j++)
            bfv[j] = *(const s16x8*)&Bs[(quad * TN + wn + j * 16 + fr) * 8];
#pragma unroll
        for (int i = 0; i < 4; i++)
#pragma unroll
            for (int j = 0; j < JN; j++)
                acc[i][j] = __builtin_amdgcn_mfma_f32_16x16x32_bf16(af[i], bfv[j], acc[i][j], 0, 0, 0);
    }

    const int rb = quad * 4;
#pragma unroll
    for (int i = 0; i < 4; i++)
#pragma unroll
        for (int j = 0; j < JN; j++) {
            const int col = tile_n + wn + j * 16 + fr;
#pragma unroll
            for (int r = 0; r < 4; r++) {
                const int row = tile_m + wm + i * 16 + rb + r;
                if (row < mlim)
                    C[cbase + (size_t)row * ldc + col] = f2bf(acc[i][j][r] * scale);
            }
        }
}

// ---------------------------------------------------------------------------
// combine_kv (merged, one launch): blocks [0,M_ALL) -> K path (LN),
// blocks [M_ALL, 2*M_ALL) -> V path.  G13-vectorized (uint4/float4/ushort4),
// per-path XCD-chunked bijective swizzle (r9, measured win).
// ---------------------------------------------------------------------------
__global__ __launch_bounds__(256) void combine_kv(
    const unsigned int* __restrict__ Yk, const unsigned int* __restrict__ Yv,
    const float* __restrict__ kb, const float* __restrict__ vb,
    const float* __restrict__ lng, const float* __restrict__ lnb,
    bf16* __restrict__ ks, bf16* __restrict__ vs) {
    const int t = threadIdx.x, lane = t & 63, wave = t >> 6;
    int orig = blockIdx.x;
    const bool vpath = orig >= M_ALL;
    if (vpath) orig -= M_ALL;
    {
        const int qc = M_ALL >> 3, rc = M_ALL & 7;
        const int xcd = orig & 7, sub = orig >> 3;
        orig = (xcd < rc ? xcd * (qc + 1) : rc * (qc + 1) + (xcd - rc) * qc) + sub;
    }
    const int m = orig;
    int mm = m < 700 ? m : m - 700;
    int base = m < 700 ? 0 : 200;
    int nsamp = mm / LT, l = mm - nsamp * LT;
    const unsigned int* Y = vpath ? Yv : Yk;
    const uint4* ya4 = (const uint4*)(Y + (size_t)(base + nsamp * 8 + TUP_A[l]) * (N2 / 2));
    const uint4* yb4 = (const uint4*)(Y + (size_t)(base + nsamp * 8 + TUP_B[l]) * (N2 / 2));
    if (vpath) {
        const float4* vb4 = (const float4*)vb;
        for (int u = t; u < OUTD / 4; u += 256) {       // 288 slots
            uint4 a4 = ya4[u], b4 = yb4[u];
            float4 c4 = vb4[u];
            ushort4 o;
            o.x = f2bits(ubits2f(a4.x & 0xFFFFu) + ubits2f(b4.x >> 16) + c4.x);
            o.y = f2bits(ubits2f(a4.y & 0xFFFFu) + ubits2f(b4.y >> 16) + c4.y);
            o.z = f2bits(ubits2f(a4.z & 0xFFFFu) + ubits2f(b4.z >> 16) + c4.z);
            o.w = f2bits(ubits2f(a4.w & 0xFFFFu) + ubits2f(b4.w >> 16) + c4.w);
            *(ushort4*)&vs[(size_t)m * OUTD + u * 4] = o;
        }
        return;
    }
    const float4* kb4 = (const float4*)kb;
    float vals[8];                                      // <= 2 iters x 4
    int cnt = 0;
    float s = 0.f, s2 = 0.f;
    for (int u = t; u < OUTD / 4; u += 256) {
        uint4 a4 = ya4[u], b4 = yb4[u];
        float4 c4 = kb4[u];
        float v0 = ubits2f(a4.x & 0xFFFFu) + ubits2f(b4.x >> 16) + c4.x;
        float v1 = ubits2f(a4.y & 0xFFFFu) + ubits2f(b4.y >> 16) + c4.y;
        float v2 = ubits2f(a4.z & 0xFFFFu) + ubits2f(b4.z >> 16) + c4.z;
        float v3 = ubits2f(a4.w & 0xFFFFu) + ubits2f(b4.w >> 16) + c4.w;
        vals[cnt] = v0; vals[cnt + 1] = v1; vals[cnt + 2] = v2; vals[cnt + 3] = v3;
        cnt += 4;
        s += (v0 + v1) + (v2 + v3);
        s2 += v0 * v0 + v1 * v1 + v2 * v2 + v3 * v3;
    }
    for (int o = 32; o > 0; o >>= 1) { s += __shfl_xor(s, o); s2 += __shfl_xor(s2, o); }
    __shared__ float r1[4], r2[4];
    if (lane == 0) { r1[wave] = s; r2[wave] = s2; }
    __syncthreads();
    s = r1[0] + r1[1] + r1[2] + r1[3];
    s2 = r2[0] + r2[1] + r2[2] + r2[3];
    float mu = s * (1.f / OUTD);
    float var = s2 * (1.f / OUTD) - mu * mu;
    float inv = rsqrtf(fmaxf(var, 0.f) + 1e-5f);
    const float4* lg4 = (const float4*)lng;
    const float4* lb4 = (const float4*)lnb;
    cnt = 0;
    for (int u = t; u < OUTD / 4; u += 256) {
        float4 g4 = lg4[u], b4v = lb4[u];
        ushort4 o;
        o.x = f2bits((vals[cnt]     - mu) * inv * g4.x + b4v.x);
        o.y = f2bits((vals[cnt + 1] - mu) * inv * g4.y + b4v.y);
        o.z = f2bits((vals[cnt + 2] - mu) * inv * g4.z + b4v.z);
        o.w = f2bits((vals[cnt + 3] - mu) * inv * g4.w + b4v.w);
        cnt += 4;
        *(ushort4*)&ks[(size_t)m * OUTD + u * 4] = o;
    }
}

// ---------------------------------------------------------------------------
// sv_k (merged softmax + vspad, one launch, 320 threads):
//  blocks [0,SM): softmax, one WAVE per (row, class), barrier-free
//    (140 = 64+64+12 lane-slots; attn as 5 x 144-col blocks, pad zeroed).
//  blocks [SM, SM+2880): vsp[w][d][j] = vs[w*140+j][d] (j>=140 -> 0);
//    block SM also zeroes gbuf.  2880*320 == 5*OUTD*KP exactly.
// ---------------------------------------------------------------------------
__global__ __launch_bounds__(320) void sv_k(const bf16* __restrict__ sc,
                                            bf16* __restrict__ attn,
                                            const bf16* __restrict__ vs,
                                            bf16* __restrict__ vp,
                                            float* __restrict__ gbuf) {
    const int t = threadIdx.x;
    if (blockIdx.x < SM) {
        const int row = blockIdx.x, w = t >> 6, lane = t & 63;
        const bf16* src = sc + (size_t)row * SN_PAD + w * 140;
        bf16* dst = attn + (size_t)row * ATT_STRIDE + w * ABLK;
        float a = bf2f(src[lane]);
        float b = bf2f(src[lane + 64]);        // lane+64 <= 127 < 140: valid
        float c = (lane < 12) ? bf2f(src[lane + 128]) : -3.0e38f;
        float m = fmaxf(fmaxf(a, b), c);
        for (int o = 32; o > 0; o >>= 1) m = fmaxf(m, __shfl_xor(m, o));
        float ea = __expf(a - m), eb = __expf(b - m);
        float ec = (lane < 12) ? __expf(c - m) : 0.f;
        float s = ea + eb + ec;
        for (int o = 32; o > 0; o >>= 1) s += __shfl_xor(s, o);
        float inv = 1.f / s;
        dst[lane] = f2bf(ea * inv);
        dst[lane + 64] = f2bf(eb * inv);
        if (lane < 16) dst[lane + 128] = f2bf(lane < 12 ? ec * inv : 0.f);
        return;
    }
    const int vb = blockIdx.x - SM;            // 0..2879
    if (vb == 0)
        for (int i = t; i < NQ * 21; i += 320) gbuf[i] = 0.f;
    int idx = vb * 320 + t;                    // < 921600 == 5*OUTD*KP
    int j = idx % KP;
    int rest = idx / KP;
    int dcol = rest % OUTD;
    int w = rest / OUTD;
    vp[idx] = (j < 140) ? vs[(size_t)(w * 140 + j) * OUTD + dcol] : f2bf(0.f);
}

// ---------------------------------------------------------------------------
// fproto_k: FUSED proto-GEMM + Gram reduction.  Replaces 4x proto gemm +
// 4x gramred and deletes the 65MB protoc buffer + its 80MB re-read.
// One block = one (query q, d-tile of 128).  Grid 200*9 = 1800, q-major
// XCD swizzle (q's 46KB attn row-block L2-resident; vsp 1.8MB L2-everywhere).
// Per block: for each class w (5): stage A = attn[q*28..+32)[w*144..+160)
// (10KB) and B = vsp[w][dtile*128..+128)[0..160) (40KB) -> 2 barriers/class;
// 5 K-steps x 4 MFMA/wave into acc[w][2][2] (fp32, 80 VGPR).  M=32 pads the
// 28 real l-rows: l>=28 rows belong to the next query and are EXCLUDED from
// stats (they're recomputed by that query's own block).  K in [140,160)
// multiplies vsp's zero columns (A-spill values never contribute).  Max A
// read = attn row 5604 (zeroed tail) -> never OOB, never NaN.
// Epilogue: per-lane 21 stats (g[15],h[5],e) over its 16 C-elems (l<28),
// wave shfl + LDS reduce, 21 atomicAdds to gbuf[q*21..] (37.8K total).
// Stats are fp32 end-to-end (reference-accurate; old path rounded protoc
// to bf16 first).
// ---------------------------------------------------------------------------
__global__ __launch_bounds__(256) void fproto_k(
    const bf16* __restrict__ attn,   // [5632][720]
    const bf16* __restrict__ vsp,    // [5][1152][160]
    const bf16* __restrict__ vs,     // [6300][1152]
    float* __restrict__ gbuf) {      // [200][21]
    const int nwg = gridDim.x;       // 1800 (%8==0 -> simple swizzle)
    int orig = blockIdx.x;
    {
        const int qc = nwg >> 3, rc = nwg & 7;
        const int xcd = orig & 7, sub = orig >> 3;
        orig = (xcd < rc ? xcd * (qc + 1) : rc * (qc + 1) + (xcd - rc) * qc) + sub;
    }
    const int q = orig / 9, dt = orig - q * 9;
    const int t = threadIdx.x, lane = t & 63, wave = t >> 6;
    const int fr = lane & 15, quad = lane >> 4;

    __shared__ unsigned short As[20 * 32 * 8];     // [kq][row][8] 10,240 B
    __shared__ unsigned short Bs[20 * 128 * 8];    // [kq][drow][8] 40,960 B
    __shared__ float red[4][21];

    const unsigned short* attn_u = (const unsigned short*)attn;
    const unsigned short* vsp_u = (const unsigned short*)vsp;

    f32x4 acc[5][2][2];
#pragma unroll
    for (int w = 0; w < 5; w++)
#pragma unroll
        for (int i = 0; i < 2; i++)
#pragma unroll
            for (int j = 0; j < 2; j++) acc[w][i][j] = {0.f, 0.f, 0.f, 0.f};

#pragma unroll
    for (int w = 0; w < 5; w++) {
        __syncthreads();                            // prev class readers done
        // A: 640 16B-slots: slot = kq*32+row (kq<20, row<32)
#pragma unroll
        for (int i = 0; i < 3; i++) {
            int slot = t + 256 * i;
            if (slot < 640) {
                int kq = slot >> 5, row = slot & 31;
                *(uint4*)&As[slot * 8] =
                    *(const uint4*)&attn_u[(size_t)(q * 28 + row) * ATT_STRIDE + w * ABLK + kq * 8];
            }
        }
        // B: 2560 16B-slots: slot = kq*128+drow
#pragma unroll
        for (int i = 0; i < 10; i++) {
            int slot = t + 256 * i;
            int kq = slot >> 7, drow = slot & 127;
            *(uint4*)&Bs[slot * 8] =
                *(const uint4*)&vsp_u[(size_t)(w * OUTD + dt * 128 + drow) * KP + kq * 8];
        }
        __syncthreads();
#pragma unroll
        for (int s = 0; s < 5; s++) {
            s16x8 af[2], bfv[2];
#pragma unroll
            for (int i = 0; i < 2; i++)
                af[i] = *(const s16x8*)&As[((s * 4 + quad) * 32 + i * 16 + fr) * 8];
#pragma unroll
            for (int j = 0; j < 2; j++)
                bfv[j] = *(const s16x8*)&Bs[((s * 4 + quad) * 128 + wave * 32 + j * 16 + fr) * 8];
#pragma unroll
            for (int i = 0; i < 2; i++)
#pragma unroll
                for (int j = 0; j < 2; j++)
                    acc[w][i][j] = __builtin_amdgcn_mfma_f32_16x16x32_bf16(af[i], bfv[j], acc[w][i][j], 0, 0, 0);
        }
    }

    // ---- stats epilogue: C[l = i*16+quad*4+r][col = wave*32+j*16+fr] ----
    float st[21];
#pragma unroll
    for (int k = 0; k < 21; k++) st[k] = 0.f;
#pragma unroll
    for (int i = 0; i < 2; i++)
#pragma unroll
        for (int r = 0; r < 4; r++) {
            const int l = i * 16 + quad * 4 + r;
            if (l < 28) {
                const size_t vrow = (size_t)(700 + q * 28 + l) * OUTD;
#pragma unroll
                for (int j = 0; j < 2; j++) {
                    const int col = dt * 128 + wave * 32 + j * 16 + fr;
                    float v = bf2f(vs[vrow + col]);
                    float pv[5];
#pragma unroll
                    for (int w = 0; w < 5; w++) pv[w] = acc[w][i][j][r];
                    st[20] += v * v;
                    int c = 0;
#pragma unroll
                    for (int a = 0; a < 5; a++) {
                        st[15 + a] += v * pv[a];
#pragma unroll
                        for (int b = a; b < 5; b++) st[c++] += pv[a] * pv[b];
                    }
                }
            }
        }
#pragma unroll
    for (int k = 0; k < 21; k++)
        for (int o = 32; o > 0; o >>= 1) st[k] += __shfl_xor(st[k], o);
    if (lane == 0)
#pragma unroll
        for (int k = 0; k < 21; k++) red[wave][k] = st[k];
    __syncthreads();
    if (t < 21)
        atomicAdd(&gbuf[q * 21 + t], red[0][t] + red[1][t] + red[2][t] + red[3][t]);
}

// ---------------------------------------------------------------------------
// out (fp32): per q -> 25 sim + 5 ori
// ---------------------------------------------------------------------------
__global__ __launch_bounds__(64) void out_k(const float* __restrict__ gbuf,
                                            float* __restrict__ out) {
    int q = blockIdx.x;
    if (threadIdx.x != 0) return;
    const float* r = gbuf + q * 21;
    float G[5][5];
    int c = 0;
    for (int a = 0; a < 5; a++)
        for (int b = a; b < 5; b++) { G[a][b] = r[c]; G[b][a] = r[c]; c++; }
    float e = r[20];
    float nrm[5];
    for (int a = 0; a < 5; a++) nrm[a] = sqrtf(fmaxf(G[a][a], 0.f));
    for (int a = 0; a < 5; a++)
        for (int b = 0; b < 5; b++)
            out[(size_t)q * 25 + a * 5 + b] = G[a][b] / fmaxf(nrm[a] * nrm[b], 1e-8f);
    for (int w = 0; w < 5; w++)
        out[5000 + (size_t)q * 5 + w] = -(e - 2.f * r[15 + w] + G[w][w]) * (1.f / 28.f);
}

// ---------------------------------------------------------------------------
extern "C" void kernel_launch(void* const* d_in, const int* in_sizes, int n_in,
                              void* d_out, int out_size, void* d_ws, size_t ws_size,
                              hipStream_t stream) {
    const float* sup = (const float*)d_in[0];
    // d_in[1] = support_labels int32 — unused (sorted equal-shot)
    const float* qry = (const float*)d_in[2];
    const float* k_w = (const float*)d_in[3];
    const float* k_b = (const float*)d_in[4];
    const float* v_w = (const float*)d_in[5];
    const float* v_b = (const float*)d_in[6];
    const float* lng = (const float*)d_in[7];
    const float* lnb = (const float*)d_in[8];
    (void)in_sizes; (void)n_in; (void)out_size; (void)ws_size;

    // layout (bytes), peak 49,421,728 (<= verified ws_size >= 54.5 MB):
    //   pexb   @0           7,864,320 (1920 rows; 1800 real)  dead after proj
    //   wbf    @7,864,320  18,874,368 (k|v bf16)              dead after proj
    //   Yk     @26,738,688  8,294,400 (1800x2304)             dead after comb_k
    //   Yv     @35,033,088  8,294,400                         dead after comb_v
    //   ks     @0          14,588,928 (6332 rows; 6300 real)  dead after scores
    //   vs     @16,220,160 14,515,200 (6300 rows)             live to end
    //   sc     @30,735,360  8,650,752 (over dead Yk/Yv head)  dead after softmax
    //   vsp    @39,386,112  1,843,200
    //   attn   @41,229,312  8,110,080 (5632 rows x 720; 5 x 144-col blocks)
    //   gbuf   @49,339,392     16,800
    //   pe     @49,356,192     65,536 (8x2048 fp32 table)
    //   (protoc eliminated — fproto_k keeps proto in registers)
    char* ws = (char*)d_ws;
    bf16* pexb   = (bf16*)(ws + 0);
    bf16* wbf    = (bf16*)(ws + 7864320);
    bf16* Yk     = (bf16*)(ws + 26738688);
    bf16* Yv     = (bf16*)(ws + 35033088);
    bf16* ks     = (bf16*)(ws + 0);
    bf16* vs     = (bf16*)(ws + 16220160);
    bf16* sc     = (bf16*)(ws + 30735360);
    bf16* vsp    = (bf16*)(ws + 39386112);
    bf16* attn   = (bf16*)(ws + 41229312);
    float* gbuf  = (float*)(ws + 49339392);
    float* pe    = (float*)(ws + 49356192);

    pe_k<<<dim3(64), dim3(256), 0, stream>>>(pe, attn + (size_t)SM * ATT_STRIDE);
    pex_k<<<dim3(1800), dim3(256), 0, stream>>>(sup, qry, pe, pexb);
    wconv2_k<<<dim3(9216), dim3(256), 0, stream>>>(
        (const float4*)k_w, (const float4*)v_w, (ushort4*)wbf);

    // fused K+V projection: z in {k,v}; Y[1800,2304] = pexb @ W_view^T
    // TN=128: measured 71.7us (r6/r8) vs 84us TN=64 (r7) on this call site.
    gemm_bt<128><<<dim3(15, 18, 2), dim3(256), 0, stream>>>(
        pexb, DM, 0, wbf, DM, (size_t)4718592,
        1.0f, Yk, N2, (size_t)4147200, DM, 1800);

    combine_kv<<<dim3(2 * M_ALL), dim3(256), 0, stream>>>(
        (const unsigned int*)Yk, (const unsigned int*)Yv,
        k_b, v_b, lng, lnb, ks, vs);

    // scores: ks_q[5632,1152] @ ks_s[768,1152]^T / sqrt(1152)  (TN=64, r7)
    gemm_bt<64><<<dim3(44, 12, 1), dim3(256), 0, stream>>>(
        ks + (size_t)700 * OUTD, OUTD, 0, ks, OUTD, 0,
        0.029462782549439484f, sc, SN_PAD, 0, OUTD, 5632);

    // merged softmax (5600 blocks) + vspad (2880 blocks), 320 threads
    sv_k<<<dim3(SM + 2880), dim3(320), 0, stream>>>(sc, attn, vs, vsp, gbuf);

    // fused proto + Gram stats: one launch replaces 4x(gemm+gramred)
    fproto_k<<<dim3(1800), dim3(256), 0, stream>>>(attn, vsp, vs, gbuf);

    out_k<<<dim3(NQ), dim3(64), 0, stream>>>(gbuf, (float*)d_out);
}

// Round 12
// 289.725 us; speedup vs baseline: 1.6640x; 1.0136x over previous
//
#include <hip/hip_runtime.h>
#include <hip/hip_bf16.h>
#include <math.h>

typedef __hip_bfloat16 bf16;
typedef short s16x8 __attribute__((ext_vector_type(8)));
typedef float f32x4 __attribute__((ext_vector_type(4)));

#define NQ 200
#define SEQ 8
#define DM 2048
#define OUTD 1152
#define LT 28
#define M_ALL 6300
#define SM 5600
#define SN_PAD 768
#define ATT_STRIDE 720
#define N2 2304          // W viewed as [2304, 2048]
#define KP 160
#define ABLK 144         // attn per-class column block (16B-aligned)

__device__ __forceinline__ float bf2f(bf16 v) { return __bfloat162float(v); }
__device__ __forceinline__ bf16 f2bf(float v) { return __float2bfloat16(v); }
__device__ __forceinline__ float ubits2f(unsigned int u16) {
    unsigned int i = u16 << 16;
    float f; __builtin_memcpy(&f, &i, 4); return f;
}
__device__ __forceinline__ unsigned short f2bits(float f) {
    bf16 b = __float2bfloat16(f);
    unsigned short u; __builtin_memcpy(&u, &b, 2); return u;
}

__device__ const int TUP_A[LT] = {0,0,0,0,0,0,0,1,1,1,1,1,1,2,2,2,2,2,3,3,3,3,4,4,4,5,5,6};
__device__ const int TUP_B[LT] = {1,2,3,4,5,6,7,2,3,4,5,6,7,3,4,5,6,7,4,5,6,7,5,6,7,6,7,7};

// ---------------------------------------------------------------------------
// fused weight convert + PE table (one launch): all 9216 blocks convert
// [k_w | v_w] fp32 -> bf16; blocks 0..63 ALSO build pe[s][d] (8x2048 fp32,
// trig once) and zero attn tail rows 5600..5631 (fproto's q=199 block reads
// up to row 5604 incl. k-spill -> must be finite/zero).
// ---------------------------------------------------------------------------
__global__ __launch_bounds__(256) void wconv2_k(const float4* __restrict__ kw,
                                                const float4* __restrict__ vw,
                                                ushort4* __restrict__ o,
                                                float* __restrict__ pe,
                                                bf16* __restrict__ attn_tail) {
    int i = blockIdx.x * 256 + threadIdx.x;     // 0 .. 2,359,295
    float4 v = (i < 1179648) ? kw[i] : vw[i - 1179648];
    ushort4 r;
    r.x = f2bits(v.x); r.y = f2bits(v.y); r.z = f2bits(v.z); r.w = f2bits(v.w);
    o[i] = r;
    if (blockIdx.x < 64) {
        int p = blockIdx.x * 256 + threadIdx.x; // 0 .. 16383
        int s = p >> 11, d = p & 2047;
        float dv = expf((float)(d & ~1) * (-9.210340371976184f / 2048.0f));
        float ang = (float)s * dv;
        pe[p] = (d & 1) ? cosf(ang) * 0.1f : sinf(ang) * 0.1f;
        for (int j = p; j < 32 * ATT_STRIDE; j += 64 * 256) attn_tail[j] = f2bf(0.f);
    }
}

// ---------------------------------------------------------------------------
// pexb[r][d] = fp32 src[n][s][d] + pe[s][d] -> bf16 (1800 rows, vectorized)
// ---------------------------------------------------------------------------
__global__ __launch_bounds__(256) void pex_k(const float* __restrict__ sup,
                                             const float* __restrict__ qry,
                                             const float* __restrict__ pe,
                                             bf16* __restrict__ pexb) {
    int r = blockIdx.x, t = threadIdx.x;
    int n, s;
    const float* src;
    if (r < 200) { n = r >> 3; s = r & 7; src = sup; }
    else { int rr = r - 200; n = rr >> 3; s = rr & 7; src = qry; }
    const float4* row = (const float4*)(src + ((size_t)n * SEQ + s) * DM);
    const float4* per = (const float4*)(pe + (size_t)s * DM);
    ushort4* orow = (ushort4*)(pexb + (size_t)r * DM);
    for (int d = t; d < DM / 4; d += 256) {
        float4 a = row[d], p = per[d];
        ushort4 o;
        o.x = f2bits(a.x + p.x); o.y = f2bits(a.y + p.y);
        o.z = f2bits(a.z + p.z); o.w = f2bits(a.w + p.w);
        orow[d] = o;
    }
}

// ---------------------------------------------------------------------------
// Generic MFMA bf16 GEMM: C = scale*A*B^T; z shifts A/B/C by aZ/bZ/cZ elems.
// Proven-fastest schedule: reg stage -> sync -> LDS write -> sync -> ds_read
// -> MFMA, single LDS buffer (compiler gives implicit 1-deep pipeline).
// Templated N-tile; per-call-site choice is MEASUREMENT-BACKED (r6/r7/r8):
//   TN=128: projection (K=2048, grid 540)  -> 71.7us; TN=64 there = 84us.
//   TN=64:  scores (small K, small grid) -> occupancy 19->34% paid.
// XCD-chunked bijective block swizzle kept (FETCH 104->42 MB measured).
// C rows >= mlim are not stored (M-pad garbage containment).
// ---------------------------------------------------------------------------
template <int TN>
__global__ __launch_bounds__(256) void gemm_bt(
    const bf16* __restrict__ A, int lda, size_t aZ,
    const bf16* __restrict__ B, int ldb, size_t bZ,
    float scale, bf16* __restrict__ C, int ldc, size_t cZ, int K, int mlim) {
    constexpr int JN = TN / 32;            // B-frags per wave (2 or 4)
    // ---- XCD swizzle: logical tile id lg from hw block id (bijective) ----
    const int gx = gridDim.x, gy = gridDim.y;
    const int nwg = gx * gy * (int)gridDim.z;
    const int orig = ((int)blockIdx.z * gy + blockIdx.y) * gx + blockIdx.x;
    const int qc = nwg >> 3, rc = nwg & 7;
    const int xcd = orig & 7, sub = orig >> 3;
    const int lg = (xcd < rc ? xcd * (qc + 1) : rc * (qc + 1) + (xcd - rc) * qc) + sub;
    const int bx = lg % gx;
    const int rest = lg / gx;
    const int by = rest % gy, bz = rest / gy;

    const unsigned short* Ag0 = (const unsigned short*)A + aZ * bz;
    const unsigned short* Bg0 = (const unsigned short*)B + bZ * bz;
    const size_t cbase = cZ * bz;
    const int tile_m = bx * 128, tile_n = by * TN;
    __shared__ unsigned short As[4 * 128 * 8];
    __shared__ unsigned short Bs[4 * TN * 8];
    const int t = threadIdx.x, lane = t & 63, wave = t >> 6;
    const int wm = (wave & 1) * 64, wn = (wave >> 1) * (TN / 2);
    const int srow = t >> 1, sq0 = (t & 1) * 2;
    const unsigned short* Ag = Ag0 + (size_t)(tile_m + srow) * lda + (t & 1) * 16;
    unsigned short* AsW0 = &As[((sq0 + 0) * 128 + srow) * 8];
    unsigned short* AsW1 = &As[((sq0 + 1) * 128 + srow) * 8];
    const unsigned short* Bg;
    unsigned short* BsW0;
    unsigned short* BsW1 = nullptr;
    if constexpr (TN == 128) {             // 128 rows x 4 kq: 2 uint4/thread
        Bg = Bg0 + (size_t)(tile_n + srow) * ldb + (t & 1) * 16;
        BsW0 = &Bs[((sq0 + 0) * 128 + srow) * 8];
        BsW1 = &Bs[((sq0 + 1) * 128 + srow) * 8];
    } else {                               // 64 rows x 4 kq: 1 uint4/thread
        Bg = Bg0 + (size_t)(tile_n + (t >> 2)) * ldb + (t & 3) * 8;
        BsW0 = &Bs[((t & 3) * 64 + (t >> 2)) * 8];
    }
    const int fr = lane & 15, quad = lane >> 4;

    f32x4 acc[4][JN];
#pragma unroll
    for (int i = 0; i < 4; i++)
#pragma unroll
        for (int j = 0; j < JN; j++) acc[i][j] = {0.f, 0.f, 0.f, 0.f};

    for (int k0 = 0; k0 < K; k0 += 32) {
        uint4 a0 = *(const uint4*)(Ag + k0);
        uint4 a1 = *(const uint4*)(Ag + k0 + 8);
        uint4 b0 = *(const uint4*)(Bg + k0);
        uint4 b1;
        if constexpr (TN == 128) b1 = *(const uint4*)(Bg + k0 + 8);
        __syncthreads();
        *(uint4*)AsW0 = a0; *(uint4*)AsW1 = a1;
        *(uint4*)BsW0 = b0;
        if constexpr (TN == 128) *(uint4*)BsW1 = b1;
        __syncthreads();
        s16x8 af[4], bfv[JN];
#pragma unroll
        for (int i = 0; i < 4; i++)
            af[i] = *(const s16x8*)&As[(quad * 128 + wm + i * 16 + fr) * 8];
#pragma unroll
        for (int j = 0; j < JN; j++)
            bfv[j] = *(const s16x8*)&Bs[(quad * TN + wn + j * 16 + fr) * 8];
#pragma unroll
        for (int i = 0; i < 4; i++)
#pragma unroll
            for (int j = 0; j < JN; j++)
                acc[i][j] = __builtin_amdgcn_mfma_f32_16x16x32_bf16(af[i], bfv[j], acc[i][j], 0, 0, 0);
    }

    const int rb = quad * 4;
#pragma unroll
    for (int i = 0; i < 4; i++)
#pragma unroll
        for (int j = 0; j < JN; j++) {
            const int col = tile_n + wn + j * 16 + fr;
#pragma unroll
            for (int r = 0; r < 4; r++) {
                const int row = tile_m + wm + i * 16 + rb + r;
                if (row < mlim)
                    C[cbase + (size_t)row * ldc + col] = f2bf(acc[i][j][r] * scale);
            }
        }
}

// ---------------------------------------------------------------------------
// combine_kv (merged, one launch): blocks [0,M_ALL) -> K path (LN),
// blocks [M_ALL, 2*M_ALL) -> V path.  G13-vectorized (uint4/float4/ushort4),
// per-path XCD-chunked bijective swizzle (r9, measured win).
// ---------------------------------------------------------------------------
__global__ __launch_bounds__(256) void combine_kv(
    const unsigned int* __restrict__ Yk, const unsigned int* __restrict__ Yv,
    const float* __restrict__ kb, const float* __restrict__ vb,
    const float* __restrict__ lng, const float* __restrict__ lnb,
    bf16* __restrict__ ks, bf16* __restrict__ vs) {
    const int t = threadIdx.x, lane = t & 63, wave = t >> 6;
    int orig = blockIdx.x;
    const bool vpath = orig >= M_ALL;
    if (vpath) orig -= M_ALL;
    {
        const int qc = M_ALL >> 3, rc = M_ALL & 7;
        const int xcd = orig & 7, sub = orig >> 3;
        orig = (xcd < rc ? xcd * (qc + 1) : rc * (qc + 1) + (xcd - rc) * qc) + sub;
    }
    const int m = orig;
    int mm = m < 700 ? m : m - 700;
    int base = m < 700 ? 0 : 200;
    int nsamp = mm / LT, l = mm - nsamp * LT;
    const unsigned int* Y = vpath ? Yv : Yk;
    const uint4* ya4 = (const uint4*)(Y + (size_t)(base + nsamp * 8 + TUP_A[l]) * (N2 / 2));
    const uint4* yb4 = (const uint4*)(Y + (size_t)(base + nsamp * 8 + TUP_B[l]) * (N2 / 2));
    if (vpath) {
        const float4* vb4 = (const float4*)vb;
        for (int u = t; u < OUTD / 4; u += 256) {       // 288 slots
            uint4 a4 = ya4[u], b4 = yb4[u];
            float4 c4 = vb4[u];
            ushort4 o;
            o.x = f2bits(ubits2f(a4.x & 0xFFFFu) + ubits2f(b4.x >> 16) + c4.x);
            o.y = f2bits(ubits2f(a4.y & 0xFFFFu) + ubits2f(b4.y >> 16) + c4.y);
            o.z = f2bits(ubits2f(a4.z & 0xFFFFu) + ubits2f(b4.z >> 16) + c4.z);
            o.w = f2bits(ubits2f(a4.w & 0xFFFFu) + ubits2f(b4.w >> 16) + c4.w);
            *(ushort4*)&vs[(size_t)m * OUTD + u * 4] = o;
        }
        return;
    }
    const float4* kb4 = (const float4*)kb;
    float vals[8];                                      // <= 2 iters x 4
    int cnt = 0;
    float s = 0.f, s2 = 0.f;
    for (int u = t; u < OUTD / 4; u += 256) {
        uint4 a4 = ya4[u], b4 = yb4[u];
        float4 c4 = kb4[u];
        float v0 = ubits2f(a4.x & 0xFFFFu) + ubits2f(b4.x >> 16) + c4.x;
        float v1 = ubits2f(a4.y & 0xFFFFu) + ubits2f(b4.y >> 16) + c4.y;
        float v2 = ubits2f(a4.z & 0xFFFFu) + ubits2f(b4.z >> 16) + c4.z;
        float v3 = ubits2f(a4.w & 0xFFFFu) + ubits2f(b4.w >> 16) + c4.w;
        vals[cnt] = v0; vals[cnt + 1] = v1; vals[cnt + 2] = v2; vals[cnt + 3] = v3;
        cnt += 4;
        s += (v0 + v1) + (v2 + v3);
        s2 += v0 * v0 + v1 * v1 + v2 * v2 + v3 * v3;
    }
    for (int o = 32; o > 0; o >>= 1) { s += __shfl_xor(s, o); s2 += __shfl_xor(s2, o); }
    __shared__ float r1[4], r2[4];
    if (lane == 0) { r1[wave] = s; r2[wave] = s2; }
    __syncthreads();
    s = r1[0] + r1[1] + r1[2] + r1[3];
    s2 = r2[0] + r2[1] + r2[2] + r2[3];
    float mu = s * (1.f / OUTD);
    float var = s2 * (1.f / OUTD) - mu * mu;
    float inv = rsqrtf(fmaxf(var, 0.f) + 1e-5f);
    const float4* lg4 = (const float4*)lng;
    const float4* lb4 = (const float4*)lnb;
    cnt = 0;
    for (int u = t; u < OUTD / 4; u += 256) {
        float4 g4 = lg4[u], b4v = lb4[u];
        ushort4 o;
        o.x = f2bits((vals[cnt]     - mu) * inv * g4.x + b4v.x);
        o.y = f2bits((vals[cnt + 1] - mu) * inv * g4.y + b4v.y);
        o.z = f2bits((vals[cnt + 2] - mu) * inv * g4.z + b4v.z);
        o.w = f2bits((vals[cnt + 3] - mu) * inv * g4.w + b4v.w);
        cnt += 4;
        *(ushort4*)&ks[(size_t)m * OUTD + u * 4] = o;
    }
}

// ---------------------------------------------------------------------------
// sv_k (merged softmax + vspad, one launch, 320 threads):
//  blocks [0,SM): softmax, one WAVE per (row, class), barrier-free
//    (140 = 64+64+12 lane-slots; attn as 5 x 144-col blocks, pad zeroed).
//  blocks [SM, SM+2880): vsp[w][d][j] = vs[w*140+j][d] (j>=140 -> 0);
//    block SM also zeroes gbuf.  2880*320 == 5*OUTD*KP exactly.
// ---------------------------------------------------------------------------
__global__ __launch_bounds__(320) void sv_k(const bf16* __restrict__ sc,
                                            bf16* __restrict__ attn,
                                            const bf16* __restrict__ vs,
                                            bf16* __restrict__ vp,
                                            float* __restrict__ gbuf) {
    const int t = threadIdx.x;
    if (blockIdx.x < SM) {
        const int row = blockIdx.x, w = t >> 6, lane = t & 63;
        const bf16* src = sc + (size_t)row * SN_PAD + w * 140;
        bf16* dst = attn + (size_t)row * ATT_STRIDE + w * ABLK;
        float a = bf2f(src[lane]);
        float b = bf2f(src[lane + 64]);        // lane+64 <= 127 < 140: valid
        float c = (lane < 12) ? bf2f(src[lane + 128]) : -3.0e38f;
        float m = fmaxf(fmaxf(a, b), c);
        for (int o = 32; o > 0; o >>= 1) m = fmaxf(m, __shfl_xor(m, o));
        float ea = __expf(a - m), eb = __expf(b - m);
        float ec = (lane < 12) ? __expf(c - m) : 0.f;
        float s = ea + eb + ec;
        for (int o = 32; o > 0; o >>= 1) s += __shfl_xor(s, o);
        float inv = 1.f / s;
        dst[lane] = f2bf(ea * inv);
        dst[lane + 64] = f2bf(eb * inv);
        if (lane < 16) dst[lane + 128] = f2bf(lane < 12 ? ec * inv : 0.f);
        return;
    }
    const int vb = blockIdx.x - SM;            // 0..2879
    if (vb == 0)
        for (int i = t; i < NQ * 21; i += 320) gbuf[i] = 0.f;
    int idx = vb * 320 + t;                    // < 921600 == 5*OUTD*KP
    int j = idx % KP;
    int rest = idx / KP;
    int dcol = rest % OUTD;
    int w = rest / OUTD;
    vp[idx] = (j < 140) ? vs[(size_t)(w * 140 + j) * OUTD + dcol] : f2bf(0.f);
}

// ---------------------------------------------------------------------------
// fproto_k v2: FUSED proto-GEMM + Gram reduction (replaced 4x gemm +
// 4x gramred in r11; this revision cuts staging overhead).
// One block = one (query q, d-tile of 128).  Grid 1800, q-major XCD swizzle.
// r11 structure was 5 classes x (50KB stage + 2 barriers) = 10 barriers and
// 13 ld + 13 ds_write per thread per class.  v2:
//  (a) A (attn rows) for ALL 5 classes staged ONCE: 5x[20 kq][32 rows] =
//      50KB LDS, 2 barriers per block TOTAL (A is wave-shared -> LDS earns
//      its keep).
//  (b) B (vsp) fragments read DIRECTLY global->VGPR: each wave's 32 vsp rows
//      are read by NO other wave (zero cross-wave sharing -> LDS was pure
//      overhead).  vsp is L2-resident (1.8MB, heavy cross-q reuse); the 10
//      frag loads per class are independent and issued up-front (40 VGPR).
//      [Unlike r5's LDS-free failure: 64B-granular L2 hits + 12 waves/CU.]
// M=32 pads the 28 real l-rows; l>=28 excluded from stats (recomputed by
// the next query's own block).  K in [140,160) multiplies vsp's zero cols.
// Max A read = attn row 5604 (zeroed tail) -> never OOB/NaN.
// Epilogue (unchanged from r11, verified): per-lane 21 stats over l<28,
// wave shfl + LDS reduce, 21 atomicAdds to gbuf[q*21..].  fp32 end-to-end.
// ---------------------------------------------------------------------------
__global__ __launch_bounds__(256) void fproto_k(
    const bf16* __restrict__ attn,   // [5632][720]
    const bf16* __restrict__ vsp,    // [5][1152][160]
    const bf16* __restrict__ vs,     // [6300][1152]
    float* __restrict__ gbuf) {      // [200][21]
    const int nwg = gridDim.x;       // 1800
    int orig = blockIdx.x;
    {
        const int qc = nwg >> 3, rc = nwg & 7;
        const int xcd = orig & 7, sub = orig >> 3;
        orig = (xcd < rc ? xcd * (qc + 1) : rc * (qc + 1) + (xcd - rc) * qc) + sub;
    }
    const int q = orig / 9, dt = orig - q * 9;
    const int t = threadIdx.x, lane = t & 63, wave = t >> 6;
    const int fr = lane & 15, quad = lane >> 4;

    __shared__ unsigned short As5[5 * 20 * 32 * 8];   // 51,200 B
    __shared__ float red[4][21];

    const unsigned short* attn_u = (const unsigned short*)attn;
    const unsigned short* vsp_u = (const unsigned short*)vsp;

    // stage ALL classes' A once: slot = w*640 + kq*32 + row  (3200 slots)
    for (int slot = t; slot < 3200; slot += 256) {
        int w = slot / 640, rem = slot - w * 640;
        int kq = rem >> 5, row = rem & 31;
        *(uint4*)&As5[slot * 8] =
            *(const uint4*)&attn_u[(size_t)(q * 28 + row) * ATT_STRIDE + w * ABLK + kq * 8];
    }
    __syncthreads();

    f32x4 acc[5][2][2];
#pragma unroll
    for (int w = 0; w < 5; w++)
#pragma unroll
        for (int i = 0; i < 2; i++)
#pragma unroll
            for (int j = 0; j < 2; j++) acc[w][i][j] = {0.f, 0.f, 0.f, 0.f};

    // per-lane B base: row (dt*128 + wave*32 + fr), kq-offset quad*8
    const unsigned short* vbase =
        vsp_u + (size_t)(dt * 128 + wave * 32 + fr) * KP + quad * 8;

#pragma unroll
    for (int w = 0; w < 5; w++) {
        s16x8 bfv[5][2];                        // issue all 10 loads up-front
#pragma unroll
        for (int s = 0; s < 5; s++)
#pragma unroll
            for (int j = 0; j < 2; j++)
                bfv[s][j] = *(const s16x8*)(vbase
                    + (size_t)w * OUTD * KP + (size_t)j * 16 * KP + s * 32);
#pragma unroll
        for (int s = 0; s < 5; s++) {
            s16x8 af[2];
#pragma unroll
            for (int i = 0; i < 2; i++)
                af[i] = *(const s16x8*)&As5[(w * 640 + (s * 4 + quad) * 32 + i * 16 + fr) * 8];
#pragma unroll
            for (int i = 0; i < 2; i++)
#pragma unroll
                for (int j = 0; j < 2; j++)
                    acc[w][i][j] = __builtin_amdgcn_mfma_f32_16x16x32_bf16(af[i], bfv[s][j], acc[w][i][j], 0, 0, 0);
        }
    }

    // ---- stats epilogue: C[l = i*16+quad*4+r][col = wave*32+j*16+fr] ----
    float st[21];
#pragma unroll
    for (int k = 0; k < 21; k++) st[k] = 0.f;
#pragma unroll
    for (int i = 0; i < 2; i++)
#pragma unroll
        for (int r = 0; r < 4; r++) {
            const int l = i * 16 + quad * 4 + r;
            if (l < 28) {
                const size_t vrow = (size_t)(700 + q * 28 + l) * OUTD;
#pragma unroll
                for (int j = 0; j < 2; j++) {
                    const int col = dt * 128 + wave * 32 + j * 16 + fr;
                    float v = bf2f(vs[vrow + col]);
                    float pv[5];
#pragma unroll
                    for (int w = 0; w < 5; w++) pv[w] = acc[w][i][j][r];
                    st[20] += v * v;
                    int c = 0;
#pragma unroll
                    for (int a = 0; a < 5; a++) {
                        st[15 + a] += v * pv[a];
#pragma unroll
                        for (int b = a; b < 5; b++) st[c++] += pv[a] * pv[b];
                    }
                }
            }
        }
#pragma unroll
    for (int k = 0; k < 21; k++)
        for (int o = 32; o > 0; o >>= 1) st[k] += __shfl_xor(st[k], o);
    if (lane == 0)
#pragma unroll
        for (int k = 0; k < 21; k++) red[wave][k] = st[k];
    __syncthreads();
    if (t < 21)
        atomicAdd(&gbuf[q * 21 + t], red[0][t] + red[1][t] + red[2][t] + red[3][t]);
}

// ---------------------------------------------------------------------------
// out (fp32): per q -> 25 sim + 5 ori
// ---------------------------------------------------------------------------
__global__ __launch_bounds__(64) void out_k(const float* __restrict__ gbuf,
                                            float* __restrict__ out) {
    int q = blockIdx.x;
    if (threadIdx.x != 0) return;
    const float* r = gbuf + q * 21;
    float G[5][5];
    int c = 0;
    for (int a = 0; a < 5; a++)
        for (int b = a; b < 5; b++) { G[a][b] = r[c]; G[b][a] = r[c]; c++; }
    float e = r[20];
    float nrm[5];
    for (int a = 0; a < 5; a++) nrm[a] = sqrtf(fmaxf(G[a][a], 0.f));
    for (int a = 0; a < 5; a++)
        for (int b = 0; b < 5; b++)
            out[(size_t)q * 25 + a * 5 + b] = G[a][b] / fmaxf(nrm[a] * nrm[b], 1e-8f);
    for (int w = 0; w < 5; w++)
        out[5000 + (size_t)q * 5 + w] = -(e - 2.f * r[15 + w] + G[w][w]) * (1.f / 28.f);
}

// ---------------------------------------------------------------------------
extern "C" void kernel_launch(void* const* d_in, const int* in_sizes, int n_in,
                              void* d_out, int out_size, void* d_ws, size_t ws_size,
                              hipStream_t stream) {
    const float* sup = (const float*)d_in[0];
    // d_in[1] = support_labels int32 — unused (sorted equal-shot)
    const float* qry = (const float*)d_in[2];
    const float* k_w = (const float*)d_in[3];
    const float* k_b = (const float*)d_in[4];
    const float* v_w = (const float*)d_in[5];
    const float* v_b = (const float*)d_in[6];
    const float* lng = (const float*)d_in[7];
    const float* lnb = (const float*)d_in[8];
    (void)in_sizes; (void)n_in; (void)out_size; (void)ws_size;

    // layout (bytes), peak 49,421,728 (<= verified ws_size >= 54.5 MB):
    //   pexb   @0           7,864,320 (1920 rows; 1800 real)  dead after proj
    //   wbf    @7,864,320  18,874,368 (k|v bf16)              dead after proj
    //   Yk     @26,738,688  8,294,400 (1800x2304)             dead after comb_k
    //   Yv     @35,033,088  8,294,400                         dead after comb_v
    //   ks     @0          14,588,928 (6332 rows; 6300 real)  dead after scores
    //   vs     @16,220,160 14,515,200 (6300 rows)             live to end
    //   sc     @30,735,360  8,650,752 (over dead Yk/Yv head)  dead after softmax
    //   vsp    @39,386,112  1,843,200
    //   attn   @41,229,312  8,110,080 (5632 rows x 720; 5 x 144-col blocks)
    //   gbuf   @49,339,392     16,800
    //   pe     @49,356,192     65,536 (8x2048 fp32 table)
    //   (protoc eliminated — fproto_k keeps proto in registers)
    char* ws = (char*)d_ws;
    bf16* pexb   = (bf16*)(ws + 0);
    bf16* wbf    = (bf16*)(ws + 7864320);
    bf16* Yk     = (bf16*)(ws + 26738688);
    bf16* Yv     = (bf16*)(ws + 35033088);
    bf16* ks     = (bf16*)(ws + 0);
    bf16* vs     = (bf16*)(ws + 16220160);
    bf16* sc     = (bf16*)(ws + 30735360);
    bf16* vsp    = (bf16*)(ws + 39386112);
    bf16* attn   = (bf16*)(ws + 41229312);
    float* gbuf  = (float*)(ws + 49339392);
    float* pe    = (float*)(ws + 49356192);

    // wconv2 first (it also builds pe + zeroes attn tail); pex needs pe.
    wconv2_k<<<dim3(9216), dim3(256), 0, stream>>>(
        (const float4*)k_w, (const float4*)v_w, (ushort4*)wbf,
        pe, attn + (size_t)SM * ATT_STRIDE);
    pex_k<<<dim3(1800), dim3(256), 0, stream>>>(sup, qry, pe, pexb);

    // fused K+V projection: z in {k,v}; Y[1800,2304] = pexb @ W_view^T
    // TN=128: measured 71.7us (r6/r8) vs 84us TN=64 (r7) on this call site.
    gemm_bt<128><<<dim3(15, 18, 2), dim3(256), 0, stream>>>(
        pexb, DM, 0, wbf, DM, (size_t)4718592,
        1.0f, Yk, N2, (size_t)4147200, DM, 1800);

    combine_kv<<<dim3(2 * M_ALL), dim3(256), 0, stream>>>(
        (const unsigned int*)Yk, (const unsigned int*)Yv,
        k_b, v_b, lng, lnb, ks, vs);

    // scores: ks_q[5632,1152] @ ks_s[768,1152]^T / sqrt(1152)  (TN=64, r7)
    gemm_bt<64><<<dim3(44, 12, 1), dim3(256), 0, stream>>>(
        ks + (size_t)700 * OUTD, OUTD, 0, ks, OUTD, 0,
        0.029462782549439484f, sc, SN_PAD, 0, OUTD, 5632);

    // merged softmax (5600 blocks) + vspad (2880 blocks), 320 threads
    sv_k<<<dim3(SM + 2880), dim3(320), 0, stream>>>(sc, attn, vs, vsp, gbuf);

    // fused proto + Gram stats: one launch replaces 4x(gemm+gramred)
    fproto_k<<<dim3(1800), dim3(256), 0, stream>>>(attn, vsp, vs, gbuf);

    out_k<<<dim3(NQ), dim3(64), 0, stream>>>(gbuf, (float*)d_out);
}